// Round 12
// baseline (752.187 us; speedup 1.0000x reference)
//
#include <hip/hip_runtime.h>

#define NRUNS 4
#define NAU 50000
#define NPP 100000
#define NEDGE 500000
#define HD 128
#define INV_KEEP 1.25f
#define BN_EPS 1e-5f
#define LDA 136      // padded LDS row (bf16 elems), 272B
#define NB_GEMM 1280 // persistent GEMM grid (5 blocks/CU)

#define M_PROJ   0   // masked 4-copy projection (fallback path)
#define M_GIN1   1   // fallback GIN stage-1 (separate f32 agg)
#define M_GIN2   2   // BN(from stats)+relu + W2 + relu
#define M_PROJ1  3   // single-copy unmasked projection (main path)
#define M_GIN1F0 4   // layer-0 GIN1, FUSED masked gather from proj
#define M_GIN1F1 5   // layer-1 GIN1, FUSED gather from h; run0 out -> alt

#define C_AP ((NPP + 1023) / 1024)   // 98 scan chunks, graph ap
#define C_PA ((NAU + 1023) / 1024)   // 49 scan chunks, graph pa

typedef unsigned short bf16r;
typedef __attribute__((ext_vector_type(8))) short v8s;   // 8 bf16 (4 VGPR)
typedef __attribute__((ext_vector_type(4))) float v4f;   // 4 f32 acc

__device__ inline float bf2f(bf16r u) {
    return __uint_as_float(((unsigned)u) << 16);
}
__device__ inline bf16r f2bf(float f) {
    __bf16 b = (__bf16)f;
    return __builtin_bit_cast(bf16r, b);
}

__global__ __launch_bounds__(256)
void zero_k(float* p, long n4) {
    long i = (long)blockIdx.x * 256 + threadIdx.x;
    long stride = (long)gridDim.x * 256;
    float4 z = make_float4(0.f, 0.f, 0.f, 0.f);
    for (; i < n4; i += stride) ((float4*)p)[i] = z;
}

// weight convert (blocks 0..639) + zero stats (block 640) + zero CSR cur
// arrays (blocks 641..787).
__global__ __launch_bounds__(256)
void convw_prep_k(const float* __restrict__ lin_a_w, const float* __restrict__ lin_p_w,
                  const float* __restrict__ W1, const float* __restrict__ W2,
                  bf16r* __restrict__ wt, float* __restrict__ stats,
                  float* __restrict__ curz, int curz4)
{
    int b = blockIdx.x;
    if (b < 640) {
        int t = b >> 6;
        int e = (b & 63) * 256 + threadIdx.x;
        const float* src;
        if (t == 0) src = lin_a_w;
        else if (t == 1) src = lin_p_w;
        else if (t < 6) src = W1 + (size_t)(t - 2) * HD * HD;
        else src = W2 + (size_t)(t - 6) * HD * HD;
        int n = e >> 7, k = e & 127;
        wt[(size_t)t * HD * HD + e] = f2bf(src[(size_t)k * HD + n]);
    } else if (b == 640) {
        ((float4*)stats)[threadIdx.x] = make_float4(0.f, 0.f, 0.f, 0.f);  // 8*HD f32
    } else {
        int i = (b - 641) * 256 + threadIdx.x;
        if (i < curz4) ((float4*)curz)[i] = make_float4(0.f, 0.f, 0.f, 0.f);
    }
}

// ============ CSR build, both graphs per dispatch ============
__global__ __launch_bounds__(256)
void count2_k(const int* __restrict__ ei_ap, const int* __restrict__ ei_pa,
              int* curA, int* curB)
{
    int g = blockIdx.x * 256 + threadIdx.x;
    if (g < NEDGE) atomicAdd(&curA[ei_ap[NEDGE + g]], 1);
    else if (g < 2 * NEDGE) atomicAdd(&curB[ei_pa[NEDGE + (g - NEDGE)]], 1);
}

__global__ __launch_bounds__(256)
void scan1m_k(const int* __restrict__ curA, int* offA,
              const int* __restrict__ curB, int* offB, int* partial)
{
    __shared__ int lds[256];
    int b = blockIdx.x, t = threadIdx.x;
    const int* in; int* out; int n, chunk;
    if (b < C_AP) { in = curA; out = offA; n = NPP; chunk = b; }
    else          { in = curB; out = offB; n = NAU; chunk = b - C_AP; }
    int base = chunk * 1024 + t * 4;
    int v0 = 0, v1 = 0, v2 = 0, v3 = 0;
    if (base + 3 < n) {
        int4 x = *(const int4*)(in + base);
        v0 = x.x; v1 = x.y; v2 = x.z; v3 = x.w;
    } else {
        if (base + 0 < n) v0 = in[base + 0];
        if (base + 1 < n) v1 = in[base + 1];
        if (base + 2 < n) v2 = in[base + 2];
        if (base + 3 < n) v3 = in[base + 3];
    }
    int s = v0 + v1 + v2 + v3;
    lds[t] = s;
    __syncthreads();
    for (int d = 1; d < 256; d <<= 1) {
        int x = (t >= d) ? lds[t - d] : 0;
        __syncthreads();
        lds[t] += x;
        __syncthreads();
    }
    int excl = lds[t] - s;
    if (base + 0 < n) out[base + 0] = excl;
    if (base + 1 < n) out[base + 1] = excl + v0;
    if (base + 2 < n) out[base + 2] = excl + v0 + v1;
    if (base + 3 < n) out[base + 3] = excl + v0 + v1 + v2;
    if (t == 255) partial[b] = lds[255];
}

__global__ __launch_bounds__(256)
void scan2m_k(int* partial)
{
    __shared__ int lds[256];
    int t = threadIdx.x;
    int base = blockIdx.x == 0 ? 0 : C_AP;
    int n = blockIdx.x == 0 ? C_AP : C_PA;
    int s = (t < n) ? partial[base + t] : 0;
    lds[t] = s;
    __syncthreads();
    for (int d = 1; d < 256; d <<= 1) {
        int x = (t >= d) ? lds[t - d] : 0;
        __syncthreads();
        lds[t] += x;
        __syncthreads();
    }
    if (t < n) partial[base + t] = lds[t] - s;
}

__global__ __launch_bounds__(256)
void scan3m_k(int* offA, int* curA, int* offB, int* curB,
              const int* __restrict__ partial)
{
    int b = blockIdx.x, t = threadIdx.x;
    int* off; int* cur; int n, chunk;
    if (b < C_AP) { off = offA; cur = curA; n = NPP; chunk = b; }
    else          { off = offB; cur = curB; n = NAU; chunk = b - C_AP; }
    int add = partial[b];
    int base = chunk * 1024 + t * 4;
    #pragma unroll
    for (int j = 0; j < 4; ++j) {
        int i = base + j;
        if (i < n) {
            int v = off[i] + add;
            off[i] = v;
            cur[i] = v;
        }
    }
    if (chunk == 0 && t == 0) off[n] = NEDGE;
}

__global__ __launch_bounds__(256)
void fill2_k(const int* __restrict__ ei_ap, const int* __restrict__ ei_pa,
             int* curA, int* bktA, int* curB, int* bktB)
{
    int g = blockIdx.x * 256 + threadIdx.x;
    if (g < NEDGE) {
        int d = ei_ap[NEDGE + g];
        bktA[atomicAdd(&curA[d], 1)] = ei_ap[g];
    } else if (g < 2 * NEDGE) {
        int e = g - NEDGE;
        int d = ei_pa[NEDGE + e];
        bktB[atomicAdd(&curB[d], 1)] = ei_pa[e];
    }
}

// fallback scatter (atomics, f32 agg)
__global__ __launch_bounds__(256)
void scatter_k(const bf16r* __restrict__ src, float* dst,
               const int* __restrict__ ei, int E)
{
    int g = blockIdx.x * 256 + threadIdx.x;
    int e = g >> 5, lane = g & 31;
    if (e >= E) return;
    int s = ei[e], d = ei[E + e];
    ushort4 u = *(const ushort4*)(src + (size_t)s * HD + lane * 4);
    float* dp = dst + (size_t)d * HD + lane * 4;
    unsafeAtomicAdd(dp + 0, bf2f(u.x));
    unsafeAtomicAdd(dp + 1, bf2f(u.y));
    unsafeAtomicAdd(dp + 2, bf2f(u.z));
    unsafeAtomicAdd(dp + 3, bf2f(u.w));
}

// ================= persistent pipelined MFMA GEMM =================
struct SideP {
    const void* in;       // self input (proj for F0 [node-idx], h otherwise)
    const void* in2;      // GIN2 run0 input (alt); == in when unused
    bf16r* out;
    bf16r* out2;          // F1 run0 output (alt)
    const bf16r* src;     // fused-gather neighbor source (other side)
    const int* off;
    const int* bkt;
    const float* msk0;    // source-side run0 mask (F0)
    const bf16r* wt;
    const float* bias;
    const void* agg;      // fallback GIN1 (f32)
    const float* epsp;
    float* gsum;
    float* gsumsq;
    const float* gamma;   // GIN2
    const float* beta;    // GIN2
    float invN;           // GIN2
    const float* mask;    // PROJ fallback / F0 self mask (flat [R*Nn])
    int M, Nn, tiles;
};

// Persistent strided tile loop, single-buffered LDS A-tile, 2-barrier
// schedule with register prefetch. F0/F1: run-0 ROWS (decided PER ROW —
// Nn is NOT 64-divisible, tiles straddle run boundaries) walk the CSR
// inline at staging. F1 redirects run-0 output rows to alt. GIN2 derives
// BN scale/shift from stats in-kernel; run-0 rows read from in2.
template<int MODE, typename IT, typename AT>
__global__ __launch_bounds__(256)
void mfma_gemm(SideP P, SideP A, int BP)
{
    __shared__ bf16r za[64][LDA];
    __shared__ float red[2][HD];
    const int tid = threadIdx.x;

    SideP S;
    int t, tstride;
    if ((int)blockIdx.x < BP) { S = P; t = blockIdx.x; tstride = BP; }
    else { S = A; t = (int)blockIdx.x - BP; tstride = NB_GEMM - BP; }
    if (t >= S.tiles) return;

    constexpr bool FUSED   = (MODE == M_GIN1F0 || MODE == M_GIN1F1);
    constexpr bool MASKF   = (MODE == M_GIN1F0);
    constexpr bool GIN1ANY = (MODE == M_GIN1 || FUSED);
    constexpr int  NVH     = (MODE == M_PROJ || MODE == M_PROJ1) ? 2 : 1;
    constexpr bool PAGG    = (MODE == M_GIN1);

    const int wid = tid >> 6, lane = tid & 63;
    const int lr = lane & 15, lk = (lane >> 4) * 8;
    const int colq = (lane >> 4) * 4, cb = wid * 32;
    const int srow = tid >> 4;
    const int scol = (tid & 15) * 8;

    float epsv = 1.0f;
    if (GIN1ANY) epsv = 1.0f + S.epsp[0];

    v8s w[2][4];
    #pragma unroll
    for (int cf = 0; cf < 2; ++cf)
        #pragma unroll
        for (int ks = 0; ks < 4; ++ks)
            w[cf][ks] = *(const v8s*)(S.wt + (size_t)(cb + cf * 16 + lr) * HD + ks * 32 + lk);

    const float4 bb0 = *(const float4*)(S.bias + cb + colq);
    const float4 bb1 = *(const float4*)(S.bias + cb + 16 + colq);

    // GIN2: per-thread BN scale/shift for this thread's 8 staging cols
    float sc8[MODE == M_GIN2 ? 8 : 1], sh8[MODE == M_GIN2 ? 8 : 1];
    if constexpr (MODE == M_GIN2) {
        #pragma unroll
        for (int j = 0; j < 8; ++j) {
            int c = scol + j;
            float mu = S.gsum[c] * S.invN;
            float var = S.gsumsq[c] * S.invN - mu * mu;
            float s = S.gamma[c] * rsqrtf(var + BN_EPS);
            sc8[j] = s;
            sh8[j] = S.beta[c] - mu * s;
        }
    }

    float st_s[2][4], st_q[2][4];
    if (GIN1ANY) {
        #pragma unroll
        for (int cf = 0; cf < 2; ++cf)
            #pragma unroll
            for (int j = 0; j < 4; ++j) { st_s[cf][j] = 0.f; st_q[cf][j] = 0.f; }
    }

    constexpr int NVA = (PAGG && sizeof(AT) == 4) ? 2 : 1;
    int4 pre[4][NVH];
    int4 preA[4][NVA];
    float mpre[MASKF ? 4 : 1];
    int2 offv[FUSED ? 4 : 1];

    auto prefetch = [&](int tt) {
        int m0n = tt * 64;
        #pragma unroll
        for (int i = 0; i < 4; ++i) {
            int gr = m0n + srow + 16 * i;
            // PER-ROW run (Nn not 64-divisible; tiles straddle run bounds)
            if constexpr (FUSED) {
                int run = (gr >= S.Nn) + (gr >= 2 * S.Nn) + (gr >= 3 * S.Nn);
                size_t sidx = MASKF ? (size_t)(gr - run * S.Nn) : (size_t)gr;
                pre[i][0] = *(const int4*)((const bf16r*)S.in + sidx * HD + scol);
                if constexpr (MASKF) mpre[i] = S.mask[gr];
                if (gr < S.Nn) {
                    offv[i].x = S.off[gr];
                    offv[i].y = S.off[gr + 1];
                } else {
                    offv[i] = make_int2(0, 0);   // empty gather range
                }
            } else if constexpr (MODE == M_GIN2) {
                const IT* base = (const IT*)((gr < S.Nn) ? S.in2 : S.in);
                pre[i][0] = *(const int4*)(base + (size_t)gr * HD + scol);
            } else if (gr < S.M) {
                const int4* p = (const int4*)((const IT*)S.in + (size_t)gr * HD + scol);
                pre[i][0] = p[0];
                if constexpr (NVH == 2) pre[i][1] = p[1];
            } else {
                pre[i][0] = make_int4(0, 0, 0, 0);
                if constexpr (NVH == 2) pre[i][1] = make_int4(0, 0, 0, 0);
            }
            if constexpr (PAGG) {
                if (gr < S.Nn) {
                    const int4* pa = (const int4*)((const AT*)S.agg + (size_t)gr * HD + scol);
                    preA[i][0] = pa[0];
                    if constexpr (NVA == 2) preA[i][1] = pa[1];
                } else {
                    preA[i][0] = make_int4(0, 0, 0, 0);
                    if constexpr (NVA == 2) preA[i][1] = make_int4(0, 0, 0, 0);
                }
            }
        }
    };

    prefetch(t);

    for (;;) {
        const int m0 = t * 64;
        // ---- stage ----
        #pragma unroll
        for (int i = 0; i < 4; ++i) {
            int row = srow + 16 * i;
            float v[8];
            if constexpr (NVH == 2) {
                const float* pf = (const float*)&pre[i][0];
                #pragma unroll
                for (int j = 0; j < 8; ++j) v[j] = pf[j];
            } else {
                const bf16r* pu = (const bf16r*)&pre[i][0];
                #pragma unroll
                for (int j = 0; j < 8; ++j) v[j] = bf2f(pu[j]);
            }
            if constexpr (FUSED) {
                float coef = epsv;
                if constexpr (MASKF) coef *= mpre[i] * INV_KEEP;
                float g[8];
                #pragma unroll
                for (int j = 0; j < 8; ++j) g[j] = 0.f;
                int s0 = offv[i].x, s1 = offv[i].y;   // empty for non-run0 rows
                for (int e = s0; e < s1; ++e) {
                    int idx = S.bkt[e];
                    float m = 1.0f;
                    if constexpr (MASKF) m = S.msk0[idx] * INV_KEEP;
                    const bf16r* rp = S.src + (size_t)idx * HD + scol;
                    ushort4 u0 = *(const ushort4*)rp;
                    ushort4 u1 = *(const ushort4*)(rp + 4);
                    g[0] += m * bf2f(u0.x); g[1] += m * bf2f(u0.y);
                    g[2] += m * bf2f(u0.z); g[3] += m * bf2f(u0.w);
                    g[4] += m * bf2f(u1.x); g[5] += m * bf2f(u1.y);
                    g[6] += m * bf2f(u1.z); g[7] += m * bf2f(u1.w);
                }
                #pragma unroll
                for (int j = 0; j < 8; ++j) v[j] = v[j] * coef + g[j];
            } else if constexpr (MODE == M_GIN1) {
                float av[8];
                if constexpr (sizeof(AT) == 4) {
                    const float* pa = (const float*)&preA[i][0];
                    #pragma unroll
                    for (int j = 0; j < 8; ++j) av[j] = pa[j];
                } else {
                    const bf16r* pa = (const bf16r*)&preA[i][0];
                    #pragma unroll
                    for (int j = 0; j < 8; ++j) av[j] = bf2f(pa[j]);
                }
                #pragma unroll
                for (int j = 0; j < 8; ++j) v[j] = v[j] * epsv + av[j];
            } else if constexpr (MODE == M_GIN2) {
                #pragma unroll
                for (int j = 0; j < 8; ++j)
                    v[j] = fmaxf(v[j] * sc8[j] + sh8[j], 0.f);
            }
            union { v8s w8; bf16r u[8]; } pk;
            #pragma unroll
            for (int j = 0; j < 8; ++j) pk.u[j] = f2bf(v[j]);
            *(v8s*)&za[row][scol] = pk.w8;
        }
        __syncthreads();

        // ---- prefetch next tile (stays in flight under compute) ----
        const int tn = t + tstride;
        const bool more = tn < S.tiles;
        if (more) prefetch(tn);

        // ---- compute ----
        v4f acc[2][4];
        #pragma unroll
        for (int cf = 0; cf < 2; ++cf)
            #pragma unroll
            for (int rf = 0; rf < 4; ++rf) acc[cf][rf] = (v4f){0.f, 0.f, 0.f, 0.f};

        #pragma unroll
        for (int ks = 0; ks < 4; ++ks)
            #pragma unroll
            for (int rf = 0; rf < 4; ++rf) {
                v8s a = *(const v8s*)&za[rf * 16 + lr][ks * 32 + lk];
                acc[0][rf] = __builtin_amdgcn_mfma_f32_16x16x32_bf16(w[0][ks], a, acc[0][rf], 0, 0, 0);
                acc[1][rf] = __builtin_amdgcn_mfma_f32_16x16x32_bf16(w[1][ks], a, acc[1][rf], 0, 0, 0);
            }

        #pragma unroll
        for (int rf = 0; rf < 4; ++rf) {
            acc[0][rf][0] += bb0.x; acc[0][rf][1] += bb0.y;
            acc[0][rf][2] += bb0.z; acc[0][rf][3] += bb0.w;
            acc[1][rf][0] += bb1.x; acc[1][rf][1] += bb1.y;
            acc[1][rf][2] += bb1.z; acc[1][rf][3] += bb1.w;
        }

        if constexpr (MODE == M_PROJ) {
            #pragma unroll
            for (int rf = 0; rf < 4; ++rf) {
                int grow = m0 + rf * 16 + lr;
                if (grow < S.M) {
                    #pragma unroll
                    for (int run = 0; run < NRUNS; ++run) {
                        float wm = S.mask[(size_t)run * S.Nn + grow] * INV_KEEP;
                        #pragma unroll
                        for (int cf = 0; cf < 2; ++cf) {
                            ushort4 o;
                            o.x = f2bf(acc[cf][rf][0] * wm);
                            o.y = f2bf(acc[cf][rf][1] * wm);
                            o.z = f2bf(acc[cf][rf][2] * wm);
                            o.w = f2bf(acc[cf][rf][3] * wm);
                            *(ushort4*)(S.out + ((size_t)run * S.Nn + grow) * HD + cb + cf * 16 + colq) = o;
                        }
                    }
                }
            }
        } else if constexpr (MODE == M_PROJ1) {
            #pragma unroll
            for (int rf = 0; rf < 4; ++rf) {
                int grow = m0 + rf * 16 + lr;
                if (grow < S.M) {
                    #pragma unroll
                    for (int cf = 0; cf < 2; ++cf) {
                        ushort4 o;
                        o.x = f2bf(acc[cf][rf][0]);
                        o.y = f2bf(acc[cf][rf][1]);
                        o.z = f2bf(acc[cf][rf][2]);
                        o.w = f2bf(acc[cf][rf][3]);
                        *(ushort4*)(S.out + (size_t)grow * HD + cb + cf * 16 + colq) = o;
                    }
                }
            }
        } else if constexpr (GIN1ANY) {
            #pragma unroll
            for (int rf = 0; rf < 4; ++rf) {
                int grow = m0 + rf * 16 + lr;
                bf16r* ob = S.out;
                if constexpr (MODE == M_GIN1F1) {
                    if (grow < S.Nn) ob = S.out2;   // per-row redirect
                }
                #pragma unroll
                for (int cf = 0; cf < 2; ++cf) {
                    ushort4 o;
                    o.x = f2bf(acc[cf][rf][0]);
                    o.y = f2bf(acc[cf][rf][1]);
                    o.z = f2bf(acc[cf][rf][2]);
                    o.w = f2bf(acc[cf][rf][3]);
                    *(ushort4*)(ob + (size_t)grow * HD + cb + cf * 16 + colq) = o;
                }
            }
            #pragma unroll
            for (int cf = 0; cf < 2; ++cf)
                #pragma unroll
                for (int j = 0; j < 4; ++j)
                    #pragma unroll
                    for (int rf = 0; rf < 4; ++rf) {
                        float vv = acc[cf][rf][j];
                        st_s[cf][j] += vv;
                        st_q[cf][j] += vv * vv;
                    }
        } else {  // M_GIN2
            #pragma unroll
            for (int rf = 0; rf < 4; ++rf) {
                int grow = m0 + rf * 16 + lr;
                #pragma unroll
                for (int cf = 0; cf < 2; ++cf) {
                    ushort4 o;
                    o.x = f2bf(fmaxf(acc[cf][rf][0], 0.f));
                    o.y = f2bf(fmaxf(acc[cf][rf][1], 0.f));
                    o.z = f2bf(fmaxf(acc[cf][rf][2], 0.f));
                    o.w = f2bf(fmaxf(acc[cf][rf][3], 0.f));
                    *(ushort4*)(S.out + (size_t)grow * HD + cb + cf * 16 + colq) = o;
                }
            }
        }

        if (!more) break;
        t = tn;
        __syncthreads();
    }

    if constexpr (GIN1ANY) {
        #pragma unroll
        for (int d = 1; d < 16; d <<= 1)
            #pragma unroll
            for (int cf = 0; cf < 2; ++cf)
                #pragma unroll
                for (int j = 0; j < 4; ++j) {
                    st_s[cf][j] += __shfl_xor(st_s[cf][j], d);
                    st_q[cf][j] += __shfl_xor(st_q[cf][j], d);
                }
        if (lr == 0) {
            #pragma unroll
            for (int cf = 0; cf < 2; ++cf)
                #pragma unroll
                for (int j = 0; j < 4; ++j) {
                    red[0][cb + cf * 16 + colq + j] = st_s[cf][j];
                    red[1][cb + cf * 16 + colq + j] = st_q[cf][j];
                }
        }
        __syncthreads();
        if (tid < HD) {
            unsafeAtomicAdd(S.gsum + tid, red[0][tid]);
            unsafeAtomicAdd(S.gsumsq + tid, red[1][tid]);
        }
    }
}

// mean over runs + [128]x[128,4] matmul
__global__ __launch_bounds__(256)
void final_k(const bf16r* __restrict__ ha, const float* __restrict__ fw,
             const float* __restrict__ fb, float* __restrict__ out)
{
    int g = blockIdx.x * 256 + threadIdx.x;
    int node = g >> 6, lane = g & 63;
    if (node >= NAU) return;
    float m0 = 0.f, m1 = 0.f;
    #pragma unroll
    for (int r = 0; r < NRUNS; ++r) {
        size_t base = ((size_t)r * NAU + node) * HD;
        m0 += bf2f(ha[base + lane]);
        m1 += bf2f(ha[base + 64 + lane]);
    }
    m0 *= 0.25f;
    m1 *= 0.25f;
    float p[4];
    #pragma unroll
    for (int c = 0; c < 4; ++c)
        p[c] = m0 * fw[lane * 4 + c] + m1 * fw[(lane + 64) * 4 + c];
    #pragma unroll
    for (int off = 32; off >= 1; off >>= 1)
        #pragma unroll
        for (int c = 0; c < 4; ++c) p[c] += __shfl_down(p[c], off);
    if (lane == 0) {
        #pragma unroll
        for (int c = 0; c < 4; ++c) out[(size_t)node * 4 + c] = p[c] + fb[c];
    }
}

#define CSR_INTS ((size_t)(NPP + 4) + NEDGE + (NAU + 4) + NEDGE)
#define WT_ELEMS ((size_t)10 * HD * HD)

template<bool GATHER>
static void run_all(void* const* d_in, void* d_out, void* d_ws, hipStream_t stream)
{
    const float* x_author = (const float*)d_in[0];
    const float* x_paper  = (const float*)d_in[1];
    const int*   ei_ap    = (const int*)d_in[2];
    const int*   ei_pa    = (const int*)d_in[3];
    const float* drop_a   = (const float*)d_in[4];
    const float* drop_p   = (const float*)d_in[5];
    const float* lin_a_w  = (const float*)d_in[6];
    const float* lin_a_b  = (const float*)d_in[7];
    const float* lin_p_w  = (const float*)d_in[8];
    const float* lin_p_b  = (const float*)d_in[9];
    const float* W1       = (const float*)d_in[10];
    const float* B1       = (const float*)d_in[11];
    const float* G        = (const float*)d_in[12];
    const float* BT       = (const float*)d_in[13];
    const float* W2       = (const float*)d_in[14];
    const float* B2       = (const float*)d_in[15];
    const float* EPS      = (const float*)d_in[16];
    const float* fw       = (const float*)d_in[17];
    const float* fb       = (const float*)d_in[18];

    float* stats = (float*)d_ws;                  // set t: gsum=stats+t*2*HD
    bf16r* wt = (bf16r*)(stats + 8 * HD);
    char* cp = (char*)(wt + WT_ELEMS);

    int *off_ap = nullptr, *bkt_ap = nullptr, *off_pa = nullptr, *bkt_pa = nullptr;
    if (GATHER) {
        int* ip = (int*)cp;
        off_ap = ip;  ip += NPP + 4;
        bkt_ap = ip;  ip += NEDGE;
        off_pa = ip;  ip += NAU + 4;
        bkt_pa = ip;  ip += NEDGE;
        cp = (char*)ip;
    }

    bf16r* alt_a = nullptr; bf16r* alt_p = nullptr;
    void* agg_a_v = nullptr; void* agg_p_v = nullptr;
    if (GATHER) {
        alt_a = (bf16r*)cp;  cp += (size_t)NAU * HD * sizeof(bf16r);
        alt_p = (bf16r*)cp;  cp += (size_t)NPP * HD * sizeof(bf16r);
    } else {
        agg_a_v = cp;
        agg_p_v = cp + (size_t)NAU * HD * sizeof(float);
        cp += (size_t)(NAU + NPP) * HD * sizeof(float);
    }
    bf16r* h_a = (bf16r*)cp;
    bf16r* h_p = h_a + (size_t)NRUNS * NAU * HD;

    const bf16r* wt_lin_a = wt;
    const bf16r* wt_lin_p = wt + (size_t)1 * HD * HD;
    const bf16r* wt_W1    = wt + (size_t)2 * HD * HD;
    const bf16r* wt_W2    = wt + (size_t)6 * HD * HD;

    int* cur_ap = GATHER ? (int*)alt_a : (int*)agg_a_v;
    int* cur_pa = cur_ap + NPP;
    int* partial = cur_pa + NAU;

    convw_prep_k<<<788, 256, 0, stream>>>(lin_a_w, lin_p_w, W1, W2, wt, stats,
                                          (float*)cur_ap, (NPP + NAU) / 4);

    if (GATHER) {
        count2_k<<<(2 * NEDGE + 255) / 256, 256, 0, stream>>>(ei_ap, ei_pa, cur_ap, cur_pa);
        scan1m_k<<<C_AP + C_PA, 256, 0, stream>>>(cur_ap, off_ap, cur_pa, off_pa, partial);
        scan2m_k<<<2, 256, 0, stream>>>(partial);
        scan3m_k<<<C_AP + C_PA, 256, 0, stream>>>(off_ap, cur_ap, off_pa, cur_pa, partial);
        fill2_k<<<(2 * NEDGE + 255) / 256, 256, 0, stream>>>(ei_ap, ei_pa,
                                                             cur_ap, bkt_ap, cur_pa, bkt_pa);
    }

    const int TP = NRUNS * NPP / 64, TA = NRUNS * NAU / 64;
    const int BPgin = (int)((long)NB_GEMM * TP / (TP + TA));

    if (GATHER) {
        SideP Pp = {}, Pa = {};
        Pp.in = x_paper; Pp.out = alt_p; Pp.wt = wt_lin_p; Pp.bias = lin_p_b;
        Pp.M = NPP; Pp.Nn = NPP; Pp.tiles = (NPP + 63) / 64;
        Pa.in = x_author; Pa.out = alt_a; Pa.wt = wt_lin_a; Pa.bias = lin_a_b;
        Pa.M = NAU; Pa.Nn = NAU; Pa.tiles = (NAU + 63) / 64;
        int BPproj = (int)((long)NB_GEMM * Pp.tiles / (Pp.tiles + Pa.tiles));
        mfma_gemm<M_PROJ1, float, float><<<NB_GEMM, 256, 0, stream>>>(Pp, Pa, BPproj);

        for (int l = 0; l < 2; ++l) {
            int t0 = l * 2 + 0, t1 = l * 2 + 1;

            SideP G1p = {}, G1a = {};
            G1p.wt = wt_W1 + (size_t)t0 * HD * HD;
            G1p.bias = B1 + (size_t)t0 * HD; G1p.epsp = EPS + t0;
            G1p.gsum = stats + t0 * 2 * HD; G1p.gsumsq = G1p.gsum + HD;
            G1p.M = NRUNS * NPP; G1p.Nn = NPP; G1p.tiles = TP;
            G1p.out = h_p; G1p.off = off_ap; G1p.bkt = bkt_ap;
            G1a.wt = wt_W1 + (size_t)t1 * HD * HD;
            G1a.bias = B1 + (size_t)t1 * HD; G1a.epsp = EPS + t1;
            G1a.gsum = stats + t1 * 2 * HD; G1a.gsumsq = G1a.gsum + HD;
            G1a.M = NRUNS * NAU; G1a.Nn = NAU; G1a.tiles = TA;
            G1a.out = h_a; G1a.off = off_pa; G1a.bkt = bkt_pa;
            if (l == 0) {
                G1p.in = alt_p; G1p.mask = drop_p; G1p.src = alt_a; G1p.msk0 = drop_a;
                G1a.in = alt_a; G1a.mask = drop_a; G1a.src = alt_p; G1a.msk0 = drop_p;
                mfma_gemm<M_GIN1F0, bf16r, float><<<NB_GEMM, 256, 0, stream>>>(G1p, G1a, BPgin);
            } else {
                G1p.in = h_p; G1p.src = h_a; G1p.out2 = alt_p;
                G1a.in = h_a; G1a.src = h_p; G1a.out2 = alt_a;
                mfma_gemm<M_GIN1F1, bf16r, float><<<NB_GEMM, 256, 0, stream>>>(G1p, G1a, BPgin);
            }

            SideP G2p = {}, G2a = {};
            G2p.in = h_p; G2p.in2 = (l == 0) ? (const void*)h_p : (const void*)alt_p;
            G2p.out = h_p; G2p.wt = wt_W2 + (size_t)t0 * HD * HD;
            G2p.bias = B2 + (size_t)t0 * HD;
            G2p.gsum = stats + t0 * 2 * HD; G2p.gsumsq = G2p.gsum + HD;
            G2p.gamma = G + (size_t)t0 * HD; G2p.beta = BT + (size_t)t0 * HD;
            G2p.invN = 1.0f / (NRUNS * NPP);
            G2p.M = NRUNS * NPP; G2p.Nn = NPP; G2p.tiles = TP;
            G2a.in = h_a; G2a.in2 = (l == 0) ? (const void*)h_a : (const void*)alt_a;
            G2a.out = h_a; G2a.wt = wt_W2 + (size_t)t1 * HD * HD;
            G2a.bias = B2 + (size_t)t1 * HD;
            G2a.gsum = stats + t1 * 2 * HD; G2a.gsumsq = G2a.gsum + HD;
            G2a.gamma = G + (size_t)t1 * HD; G2a.beta = BT + (size_t)t1 * HD;
            G2a.invN = 1.0f / (NRUNS * NAU);
            G2a.M = NRUNS * NAU; G2a.Nn = NAU; G2a.tiles = TA;
            mfma_gemm<M_GIN2, bf16r, float><<<NB_GEMM, 256, 0, stream>>>(G2p, G2a, BPgin);
        }
    } else {
        SideP Pp = {}, Pa = {};
        Pp.in = x_paper; Pp.out = h_p; Pp.wt = wt_lin_p; Pp.bias = lin_p_b;
        Pp.mask = drop_p; Pp.M = NPP; Pp.Nn = NPP; Pp.tiles = (NPP + 63) / 64;
        Pa.in = x_author; Pa.out = h_a; Pa.wt = wt_lin_a; Pa.bias = lin_a_b;
        Pa.mask = drop_a; Pa.M = NAU; Pa.Nn = NAU; Pa.tiles = (NAU + 63) / 64;
        int BPproj = (int)((long)NB_GEMM * Pp.tiles / (Pp.tiles + Pa.tiles));
        mfma_gemm<M_PROJ, float, float><<<NB_GEMM, 256, 0, stream>>>(Pp, Pa, BPproj);

        for (int l = 0; l < 2; ++l) {
            int t0 = l * 2 + 0, t1 = l * 2 + 1;
            zero_k<<<2048, 256, 0, stream>>>((float*)agg_a_v, ((size_t)(NAU + NPP) * HD) / 4);
            scatter_k<<<(NEDGE * 32) / 256, 256, 0, stream>>>(h_a, (float*)agg_p_v, ei_ap, NEDGE);
            scatter_k<<<(NEDGE * 32) / 256, 256, 0, stream>>>(h_p, (float*)agg_a_v, ei_pa, NEDGE);

            SideP G1p = {}, G1a = {};
            G1p.in = h_p; G1p.out = h_p; G1p.wt = wt_W1 + (size_t)t0 * HD * HD;
            G1p.bias = B1 + (size_t)t0 * HD; G1p.agg = agg_p_v; G1p.epsp = EPS + t0;
            G1p.gsum = stats + t0 * 2 * HD; G1p.gsumsq = G1p.gsum + HD;
            G1p.M = NRUNS * NPP; G1p.Nn = NPP; G1p.tiles = TP;
            G1a.in = h_a; G1a.out = h_a; G1a.wt = wt_W1 + (size_t)t1 * HD * HD;
            G1a.bias = B1 + (size_t)t1 * HD; G1a.agg = agg_a_v; G1a.epsp = EPS + t1;
            G1a.gsum = stats + t1 * 2 * HD; G1a.gsumsq = G1a.gsum + HD;
            G1a.M = NRUNS * NAU; G1a.Nn = NAU; G1a.tiles = TA;
            mfma_gemm<M_GIN1, bf16r, float><<<NB_GEMM, 256, 0, stream>>>(G1p, G1a, BPgin);

            SideP G2p = {}, G2a = {};
            G2p.in = h_p; G2p.in2 = h_p; G2p.out = h_p;
            G2p.wt = wt_W2 + (size_t)t0 * HD * HD; G2p.bias = B2 + (size_t)t0 * HD;
            G2p.gsum = stats + t0 * 2 * HD; G2p.gsumsq = G2p.gsum + HD;
            G2p.gamma = G + (size_t)t0 * HD; G2p.beta = BT + (size_t)t0 * HD;
            G2p.invN = 1.0f / (NRUNS * NPP);
            G2p.M = NRUNS * NPP; G2p.Nn = NPP; G2p.tiles = TP;
            G2a.in = h_a; G2a.in2 = h_a; G2a.out = h_a;
            G2a.wt = wt_W2 + (size_t)t1 * HD * HD; G2a.bias = B2 + (size_t)t1 * HD;
            G2a.gsum = stats + t1 * 2 * HD; G2a.gsumsq = G2a.gsum + HD;
            G2a.gamma = G + (size_t)t1 * HD; G2a.beta = BT + (size_t)t1 * HD;
            G2a.invN = 1.0f / (NRUNS * NAU);
            G2a.M = NRUNS * NAU; G2a.Nn = NAU; G2a.tiles = TA;
            mfma_gemm<M_GIN2, bf16r, float><<<NB_GEMM, 256, 0, stream>>>(G2p, G2a, BPgin);
        }
    }

    final_k<<<(NAU * 64) / 256, 256, 0, stream>>>(h_a, fw, fb, (float*)d_out);
}

extern "C" void kernel_launch(void* const* d_in, const int* in_sizes, int n_in,
                              void* d_out, int out_size, void* d_ws, size_t ws_size,
                              hipStream_t stream)
{
    const size_t hB    = (size_t)NRUNS * (NAU + NPP) * HD * sizeof(bf16r);
    const size_t statB = 8 * HD * sizeof(float);
    const size_t wtB   = WT_ELEMS * sizeof(bf16r);
    const size_t csrB  = CSR_INTS * sizeof(int);
    const size_t altB  = (size_t)(NAU + NPP) * HD * sizeof(bf16r);

    const size_t need_gather = statB + wtB + csrB + altB + hB;   // ~200 MB
    if (ws_size >= need_gather) {
        run_all<true>(d_in, d_out, d_ws, stream);
    } else {
        run_all<false>(d_in, d_out, d_ws, stream);               // atomic fallback
    }
}

// Round 13
// 603.231 us; speedup vs baseline: 1.2469x; 1.2469x over previous
//
#include <hip/hip_runtime.h>

#define NRUNS 4
#define NAU 50000
#define NPP 100000
#define NEDGE 500000
#define HD 128
#define INV_KEEP 1.25f
#define BN_EPS 1e-5f
#define LDA 136      // padded LDS row (bf16 elems), 272B
#define NB_GEMM 1280 // persistent GEMM grid (5 blocks/CU)

#define M_PROJ   0   // masked 4-copy projection (fallback path)
#define M_GIN1   1   // GIN stage-1 reading h + agg (layer >= 1 / fallback)
#define M_GIN2   2   // BN(from stats)+relu + W2 + relu, in place
#define M_PROJ1  3   // single-copy unmasked projection (main path)
#define M_GIN1M  4   // layer-0 GIN stage-1: input = mask*1.25*proj + agg

#define C_AP ((NPP + 1023) / 1024)   // 98 scan chunks, graph ap
#define C_PA ((NAU + 1023) / 1024)   // 49 scan chunks, graph pa

typedef unsigned short bf16r;
typedef __attribute__((ext_vector_type(8))) short v8s;   // 8 bf16 (4 VGPR)
typedef __attribute__((ext_vector_type(4))) float v4f;   // 4 f32 acc

__device__ inline float bf2f(bf16r u) {
    return __uint_as_float(((unsigned)u) << 16);
}
__device__ inline bf16r f2bf(float f) {
    __bf16 b = (__bf16)f;
    return __builtin_bit_cast(bf16r, b);
}

__global__ __launch_bounds__(256)
void zero_k(float* p, long n4) {
    long i = (long)blockIdx.x * 256 + threadIdx.x;
    long stride = (long)gridDim.x * 256;
    float4 z = make_float4(0.f, 0.f, 0.f, 0.f);
    for (; i < n4; i += stride) ((float4*)p)[i] = z;
}

// weight convert (blocks 0..639) + zero 4 stat sets (block 640) + zero CSR
// cur arrays (blocks 641..787). One dispatch.
__global__ __launch_bounds__(256)
void convw_prep_k(const float* __restrict__ lin_a_w, const float* __restrict__ lin_p_w,
                  const float* __restrict__ W1, const float* __restrict__ W2,
                  bf16r* __restrict__ wt, float* __restrict__ stats,
                  float* __restrict__ curz, int curz4)
{
    int b = blockIdx.x;
    if (b < 640) {
        int t = b >> 6;
        int e = (b & 63) * 256 + threadIdx.x;
        const float* src;
        if (t == 0) src = lin_a_w;
        else if (t == 1) src = lin_p_w;
        else if (t < 6) src = W1 + (size_t)(t - 2) * HD * HD;
        else src = W2 + (size_t)(t - 6) * HD * HD;
        int n = e >> 7, k = e & 127;
        wt[(size_t)t * HD * HD + e] = f2bf(src[(size_t)k * HD + n]);
    } else if (b == 640) {
        ((float4*)stats)[threadIdx.x] = make_float4(0.f, 0.f, 0.f, 0.f);  // 8*HD f32
    } else {
        int i = (b - 641) * 256 + threadIdx.x;
        if (i < curz4) ((float4*)curz)[i] = make_float4(0.f, 0.f, 0.f, 0.f);
    }
}

// ============ CSR build, both graphs per dispatch ============
__global__ __launch_bounds__(256)
void count2_k(const int* __restrict__ ei_ap, const int* __restrict__ ei_pa,
              int* curA, int* curB)
{
    int g = blockIdx.x * 256 + threadIdx.x;
    if (g < NEDGE) atomicAdd(&curA[ei_ap[NEDGE + g]], 1);
    else if (g < 2 * NEDGE) atomicAdd(&curB[ei_pa[NEDGE + (g - NEDGE)]], 1);
}

__global__ __launch_bounds__(256)
void scan1m_k(const int* __restrict__ curA, int* offA,
              const int* __restrict__ curB, int* offB, int* partial)
{
    __shared__ int lds[256];
    int b = blockIdx.x, t = threadIdx.x;
    const int* in; int* out; int n, chunk;
    if (b < C_AP) { in = curA; out = offA; n = NPP; chunk = b; }
    else          { in = curB; out = offB; n = NAU; chunk = b - C_AP; }
    int base = chunk * 1024 + t * 4;
    int v0 = 0, v1 = 0, v2 = 0, v3 = 0;
    if (base + 3 < n) {
        int4 x = *(const int4*)(in + base);
        v0 = x.x; v1 = x.y; v2 = x.z; v3 = x.w;
    } else {
        if (base + 0 < n) v0 = in[base + 0];
        if (base + 1 < n) v1 = in[base + 1];
        if (base + 2 < n) v2 = in[base + 2];
        if (base + 3 < n) v3 = in[base + 3];
    }
    int s = v0 + v1 + v2 + v3;
    lds[t] = s;
    __syncthreads();
    for (int d = 1; d < 256; d <<= 1) {
        int x = (t >= d) ? lds[t - d] : 0;
        __syncthreads();
        lds[t] += x;
        __syncthreads();
    }
    int excl = lds[t] - s;
    if (base + 0 < n) out[base + 0] = excl;
    if (base + 1 < n) out[base + 1] = excl + v0;
    if (base + 2 < n) out[base + 2] = excl + v0 + v1;
    if (base + 3 < n) out[base + 3] = excl + v0 + v1 + v2;
    if (t == 255) partial[b] = lds[255];
}

__global__ __launch_bounds__(256)
void scan2m_k(int* partial)
{
    __shared__ int lds[256];
    int t = threadIdx.x;
    int base = blockIdx.x == 0 ? 0 : C_AP;
    int n = blockIdx.x == 0 ? C_AP : C_PA;
    int s = (t < n) ? partial[base + t] : 0;
    lds[t] = s;
    __syncthreads();
    for (int d = 1; d < 256; d <<= 1) {
        int x = (t >= d) ? lds[t - d] : 0;
        __syncthreads();
        lds[t] += x;
        __syncthreads();
    }
    if (t < n) partial[base + t] = lds[t] - s;
}

__global__ __launch_bounds__(256)
void scan3m_k(int* offA, int* curA, int* offB, int* curB,
              const int* __restrict__ partial)
{
    int b = blockIdx.x, t = threadIdx.x;
    int* off; int* cur; int n, chunk;
    if (b < C_AP) { off = offA; cur = curA; n = NPP; chunk = b; }
    else          { off = offB; cur = curB; n = NAU; chunk = b - C_AP; }
    int add = partial[b];
    int base = chunk * 1024 + t * 4;
    #pragma unroll
    for (int j = 0; j < 4; ++j) {
        int i = base + j;
        if (i < n) {
            int v = off[i] + add;
            off[i] = v;
            cur[i] = v;
        }
    }
    if (chunk == 0 && t == 0) off[n] = NEDGE;
}

__global__ __launch_bounds__(256)
void fill2_k(const int* __restrict__ ei_ap, const int* __restrict__ ei_pa,
             int* curA, int* bktA, int* curB, int* bktB)
{
    int g = blockIdx.x * 256 + threadIdx.x;
    if (g < NEDGE) {
        int d = ei_ap[NEDGE + g];
        bktA[atomicAdd(&curA[d], 1)] = ei_ap[g];
    } else if (g < 2 * NEDGE) {
        int e = g - NEDGE;
        int d = ei_pa[NEDGE + e];
        bktB[atomicAdd(&curB[d], 1)] = ei_pa[e];
    }
}

// combined gather (both graphs), one 64-lane wave per dst node, f32 accum,
// bf16 store. MASKED: value = mask0[src]*1.25*src_row (layer 0, from proj).
template<bool MASKED>
__global__ __launch_bounds__(256)
void gather2_k(const bf16r* __restrict__ hA, const bf16r* __restrict__ hP,
               bf16r* __restrict__ aggP, bf16r* __restrict__ aggA,
               const int* __restrict__ offAP, const int* __restrict__ bktAP,
               const int* __restrict__ offPA, const int* __restrict__ bktPA,
               const float* __restrict__ mA0, const float* __restrict__ mP0)
{
    int gw = (blockIdx.x * 256 + threadIdx.x) >> 6;
    int lane = threadIdx.x & 63;
    const bf16r* src; bf16r* agg; const int* off; const int* bkt;
    const float* msk; int w;
    if (gw < NPP) { src = hA; agg = aggP; off = offAP; bkt = bktAP; msk = mA0; w = gw; }
    else          { src = hP; agg = aggA; off = offPA; bkt = bktPA; msk = mP0; w = gw - NPP; }
    int s0 = off[w], s1 = off[w + 1];
    float a0 = 0.f, a1 = 0.f;
    int e = s0;
    for (; e + 1 < s1; e += 2) {
        int i0 = bkt[e], i1 = bkt[e + 1];
        ushort2 u = *(const ushort2*)(src + (size_t)i0 * HD + lane * 2);
        ushort2 v = *(const ushort2*)(src + (size_t)i1 * HD + lane * 2);
        if constexpr (MASKED) {
            float m0 = msk[i0] * INV_KEEP, m1 = msk[i1] * INV_KEEP;
            a0 += m0 * bf2f(u.x) + m1 * bf2f(v.x);
            a1 += m0 * bf2f(u.y) + m1 * bf2f(v.y);
        } else {
            a0 += bf2f(u.x) + bf2f(v.x);
            a1 += bf2f(u.y) + bf2f(v.y);
        }
    }
    if (e < s1) {
        int i0 = bkt[e];
        ushort2 u = *(const ushort2*)(src + (size_t)i0 * HD + lane * 2);
        float m0 = MASKED ? msk[i0] * INV_KEEP : 1.0f;
        a0 += m0 * bf2f(u.x);
        a1 += m0 * bf2f(u.y);
    }
    ushort2 o;
    o.x = f2bf(a0);
    o.y = f2bf(a1);
    *(ushort2*)(agg + (size_t)w * HD + lane * 2) = o;
}

// fallback scatter (atomics, f32 agg)
__global__ __launch_bounds__(256)
void scatter_k(const bf16r* __restrict__ src, float* dst,
               const int* __restrict__ ei, int E)
{
    int g = blockIdx.x * 256 + threadIdx.x;
    int e = g >> 5, lane = g & 31;
    if (e >= E) return;
    int s = ei[e], d = ei[E + e];
    ushort4 u = *(const ushort4*)(src + (size_t)s * HD + lane * 4);
    float* dp = dst + (size_t)d * HD + lane * 4;
    unsafeAtomicAdd(dp + 0, bf2f(u.x));
    unsafeAtomicAdd(dp + 1, bf2f(u.y));
    unsafeAtomicAdd(dp + 2, bf2f(u.z));
    unsafeAtomicAdd(dp + 3, bf2f(u.w));
}

// ================= persistent pipelined MFMA GEMM =================
struct SideP {
    const void* in;       // self input (proj for GIN1M [node-idx], h otherwise)
    bf16r* out;
    const void* agg;      // AT-typed (bf16 main, f32 fallback)
    const bf16r* wt;
    const float* bias;
    const float* epsp;
    float* gsum;
    float* gsumsq;
    const float* gamma;   // GIN2
    const float* beta;    // GIN2
    float invN;           // GIN2
    const float* mask;    // PROJ: [R][Nn]; GIN1M: flat [R*Nn]
    int M, Nn, tiles;
};

// Persistent strided tile loop, single-buffered LDS A-tile, 2-barrier
// schedule, register prefetch of h AND agg. GIN1* accumulate BN stats in
// regs; one atomic pass per block. GIN2 derives BN scale/shift from the
// stats buffers in-kernel (no finalize dispatch).
template<int MODE, typename IT, typename AT>
__global__ __launch_bounds__(256)
void mfma_gemm(SideP P, SideP A, int BP)
{
    __shared__ bf16r za[64][LDA];
    __shared__ float red[2][HD];
    const int tid = threadIdx.x;

    SideP S;
    int t, tstride;
    if ((int)blockIdx.x < BP) { S = P; t = blockIdx.x; tstride = BP; }
    else { S = A; t = (int)blockIdx.x - BP; tstride = NB_GEMM - BP; }
    if (t >= S.tiles) return;

    constexpr bool GIN1ANY = (MODE == M_GIN1 || MODE == M_GIN1M);
    constexpr bool PMSK    = (MODE == M_GIN1M);
    constexpr int  NVH     = (MODE == M_PROJ || MODE == M_PROJ1) ? 2 : 1;
    constexpr int  NVA     = (GIN1ANY && sizeof(AT) == 4) ? 2 : 1;

    const int wid = tid >> 6, lane = tid & 63;
    const int lr = lane & 15, lk = (lane >> 4) * 8;
    const int colq = (lane >> 4) * 4, cb = wid * 32;
    const int srow = tid >> 4;
    const int scol = (tid & 15) * 8;

    float epsv = 1.0f;
    if (GIN1ANY) epsv = 1.0f + S.epsp[0];

    v8s w[2][4];
    #pragma unroll
    for (int cf = 0; cf < 2; ++cf)
        #pragma unroll
        for (int ks = 0; ks < 4; ++ks)
            w[cf][ks] = *(const v8s*)(S.wt + (size_t)(cb + cf * 16 + lr) * HD + ks * 32 + lk);

    const float4 bb0 = *(const float4*)(S.bias + cb + colq);
    const float4 bb1 = *(const float4*)(S.bias + cb + 16 + colq);

    // GIN2: per-thread BN scale/shift for this thread's 8 staging cols
    float sc8[MODE == M_GIN2 ? 8 : 1], sh8[MODE == M_GIN2 ? 8 : 1];
    if constexpr (MODE == M_GIN2) {
        #pragma unroll
        for (int j = 0; j < 8; ++j) {
            int c = scol + j;
            float mu = S.gsum[c] * S.invN;
            float var = S.gsumsq[c] * S.invN - mu * mu;
            float s = S.gamma[c] * rsqrtf(var + BN_EPS);
            sc8[j] = s;
            sh8[j] = S.beta[c] - mu * s;
        }
    }

    float st_s[2][4], st_q[2][4];
    if (GIN1ANY) {
        #pragma unroll
        for (int cf = 0; cf < 2; ++cf)
            #pragma unroll
            for (int j = 0; j < 4; ++j) { st_s[cf][j] = 0.f; st_q[cf][j] = 0.f; }
    }

    int4 pre[4][NVH];
    int4 preA[4][NVA];
    float mpre[PMSK ? 4 : 1];

    auto prefetch = [&](int tt) {
        int m0n = tt * 64;
        #pragma unroll
        for (int i = 0; i < 4; ++i) {
            int gr = m0n + srow + 16 * i;
            if constexpr (PMSK) {
                // per-row run (Nn not 64-divisible)
                int run = (gr >= S.Nn) + (gr >= 2 * S.Nn) + (gr >= 3 * S.Nn);
                int node = gr - run * S.Nn;
                mpre[i] = S.mask[gr];
                pre[i][0] = *(const int4*)((const bf16r*)S.in + (size_t)node * HD + scol);
            } else if (gr < S.M) {
                const int4* p = (const int4*)((const IT*)S.in + (size_t)gr * HD + scol);
                pre[i][0] = p[0];
                if constexpr (NVH == 2) pre[i][1] = p[1];
            } else {
                pre[i][0] = make_int4(0, 0, 0, 0);
                if constexpr (NVH == 2) pre[i][1] = make_int4(0, 0, 0, 0);
            }
            if constexpr (GIN1ANY) {
                if (gr < S.Nn) {
                    const int4* pa = (const int4*)((const AT*)S.agg + (size_t)gr * HD + scol);
                    preA[i][0] = pa[0];
                    if constexpr (NVA == 2) preA[i][1] = pa[1];
                } else {
                    preA[i][0] = make_int4(0, 0, 0, 0);
                    if constexpr (NVA == 2) preA[i][1] = make_int4(0, 0, 0, 0);
                }
            }
        }
    };

    prefetch(t);

    for (;;) {
        const int m0 = t * 64;
        // ---- stage ----
        #pragma unroll
        for (int i = 0; i < 4; ++i) {
            int row = srow + 16 * i;
            float v[8];
            if constexpr (NVH == 2) {
                const float* pf = (const float*)&pre[i][0];
                #pragma unroll
                for (int j = 0; j < 8; ++j) v[j] = pf[j];
            } else {
                const bf16r* pu = (const bf16r*)&pre[i][0];
                #pragma unroll
                for (int j = 0; j < 8; ++j) v[j] = bf2f(pu[j]);
            }
            if constexpr (GIN1ANY) {
                float av[8];
                if constexpr (sizeof(AT) == 4) {
                    const float* pa = (const float*)&preA[i][0];
                    #pragma unroll
                    for (int j = 0; j < 8; ++j) av[j] = pa[j];
                } else {
                    const bf16r* pa = (const bf16r*)&preA[i][0];
                    #pragma unroll
                    for (int j = 0; j < 8; ++j) av[j] = bf2f(pa[j]);
                }
                float coef = epsv;
                if constexpr (PMSK) coef = mpre[i] * INV_KEEP * epsv;
                #pragma unroll
                for (int j = 0; j < 8; ++j) v[j] = v[j] * coef + av[j];
            } else if constexpr (MODE == M_GIN2) {
                #pragma unroll
                for (int j = 0; j < 8; ++j)
                    v[j] = fmaxf(v[j] * sc8[j] + sh8[j], 0.f);
            }
            union { v8s w8; bf16r u[8]; } pk;
            #pragma unroll
            for (int j = 0; j < 8; ++j) pk.u[j] = f2bf(v[j]);
            *(v8s*)&za[row][scol] = pk.w8;
        }
        __syncthreads();

        // ---- prefetch next tile (stays in flight under compute) ----
        const int tn = t + tstride;
        const bool more = tn < S.tiles;
        if (more) prefetch(tn);

        // ---- compute ----
        v4f acc[2][4];
        #pragma unroll
        for (int cf = 0; cf < 2; ++cf)
            #pragma unroll
            for (int rf = 0; rf < 4; ++rf) acc[cf][rf] = (v4f){0.f, 0.f, 0.f, 0.f};

        #pragma unroll
        for (int ks = 0; ks < 4; ++ks)
            #pragma unroll
            for (int rf = 0; rf < 4; ++rf) {
                v8s a = *(const v8s*)&za[rf * 16 + lr][ks * 32 + lk];
                acc[0][rf] = __builtin_amdgcn_mfma_f32_16x16x32_bf16(w[0][ks], a, acc[0][rf], 0, 0, 0);
                acc[1][rf] = __builtin_amdgcn_mfma_f32_16x16x32_bf16(w[1][ks], a, acc[1][rf], 0, 0, 0);
            }

        #pragma unroll
        for (int rf = 0; rf < 4; ++rf) {
            acc[0][rf][0] += bb0.x; acc[0][rf][1] += bb0.y;
            acc[0][rf][2] += bb0.z; acc[0][rf][3] += bb0.w;
            acc[1][rf][0] += bb1.x; acc[1][rf][1] += bb1.y;
            acc[1][rf][2] += bb1.z; acc[1][rf][3] += bb1.w;
        }

        if constexpr (MODE == M_PROJ) {
            #pragma unroll
            for (int rf = 0; rf < 4; ++rf) {
                int grow = m0 + rf * 16 + lr;
                if (grow < S.M) {
                    #pragma unroll
                    for (int run = 0; run < NRUNS; ++run) {
                        float wm = S.mask[(size_t)run * S.Nn + grow] * INV_KEEP;
                        #pragma unroll
                        for (int cf = 0; cf < 2; ++cf) {
                            ushort4 o;
                            o.x = f2bf(acc[cf][rf][0] * wm);
                            o.y = f2bf(acc[cf][rf][1] * wm);
                            o.z = f2bf(acc[cf][rf][2] * wm);
                            o.w = f2bf(acc[cf][rf][3] * wm);
                            *(ushort4*)(S.out + ((size_t)run * S.Nn + grow) * HD + cb + cf * 16 + colq) = o;
                        }
                    }
                }
            }
        } else if constexpr (MODE == M_PROJ1) {
            #pragma unroll
            for (int rf = 0; rf < 4; ++rf) {
                int grow = m0 + rf * 16 + lr;
                if (grow < S.M) {
                    #pragma unroll
                    for (int cf = 0; cf < 2; ++cf) {
                        ushort4 o;
                        o.x = f2bf(acc[cf][rf][0]);
                        o.y = f2bf(acc[cf][rf][1]);
                        o.z = f2bf(acc[cf][rf][2]);
                        o.w = f2bf(acc[cf][rf][3]);
                        *(ushort4*)(S.out + (size_t)grow * HD + cb + cf * 16 + colq) = o;
                    }
                }
            }
        } else if constexpr (GIN1ANY) {
            #pragma unroll
            for (int rf = 0; rf < 4; ++rf) {
                int grow = m0 + rf * 16 + lr;
                #pragma unroll
                for (int cf = 0; cf < 2; ++cf) {
                    ushort4 o;
                    o.x = f2bf(acc[cf][rf][0]);
                    o.y = f2bf(acc[cf][rf][1]);
                    o.z = f2bf(acc[cf][rf][2]);
                    o.w = f2bf(acc[cf][rf][3]);
                    *(ushort4*)(S.out + (size_t)grow * HD + cb + cf * 16 + colq) = o;
                }
            }
            #pragma unroll
            for (int cf = 0; cf < 2; ++cf)
                #pragma unroll
                for (int j = 0; j < 4; ++j)
                    #pragma unroll
                    for (int rf = 0; rf < 4; ++rf) {
                        float vv = acc[cf][rf][j];
                        st_s[cf][j] += vv;
                        st_q[cf][j] += vv * vv;
                    }
        } else {  // M_GIN2
            #pragma unroll
            for (int rf = 0; rf < 4; ++rf) {
                int grow = m0 + rf * 16 + lr;
                #pragma unroll
                for (int cf = 0; cf < 2; ++cf) {
                    ushort4 o;
                    o.x = f2bf(fmaxf(acc[cf][rf][0], 0.f));
                    o.y = f2bf(fmaxf(acc[cf][rf][1], 0.f));
                    o.z = f2bf(fmaxf(acc[cf][rf][2], 0.f));
                    o.w = f2bf(fmaxf(acc[cf][rf][3], 0.f));
                    *(ushort4*)(S.out + (size_t)grow * HD + cb + cf * 16 + colq) = o;
                }
            }
        }

        if (!more) break;
        t = tn;
        __syncthreads();
    }

    if constexpr (GIN1ANY) {
        #pragma unroll
        for (int d = 1; d < 16; d <<= 1)
            #pragma unroll
            for (int cf = 0; cf < 2; ++cf)
                #pragma unroll
                for (int j = 0; j < 4; ++j) {
                    st_s[cf][j] += __shfl_xor(st_s[cf][j], d);
                    st_q[cf][j] += __shfl_xor(st_q[cf][j], d);
                }
        if (lr == 0) {
            #pragma unroll
            for (int cf = 0; cf < 2; ++cf)
                #pragma unroll
                for (int j = 0; j < 4; ++j) {
                    red[0][cb + cf * 16 + colq + j] = st_s[cf][j];
                    red[1][cb + cf * 16 + colq + j] = st_q[cf][j];
                }
        }
        __syncthreads();
        if (tid < HD) {
            unsafeAtomicAdd(S.gsum + tid, red[0][tid]);
            unsafeAtomicAdd(S.gsumsq + tid, red[1][tid]);
        }
    }
}

// mean over runs + [128]x[128,4] matmul
__global__ __launch_bounds__(256)
void final_k(const bf16r* __restrict__ ha, const float* __restrict__ fw,
             const float* __restrict__ fb, float* __restrict__ out)
{
    int g = blockIdx.x * 256 + threadIdx.x;
    int node = g >> 6, lane = g & 63;
    if (node >= NAU) return;
    float m0 = 0.f, m1 = 0.f;
    #pragma unroll
    for (int r = 0; r < NRUNS; ++r) {
        size_t base = ((size_t)r * NAU + node) * HD;
        m0 += bf2f(ha[base + lane]);
        m1 += bf2f(ha[base + 64 + lane]);
    }
    m0 *= 0.25f;
    m1 *= 0.25f;
    float p[4];
    #pragma unroll
    for (int c = 0; c < 4; ++c)
        p[c] = m0 * fw[lane * 4 + c] + m1 * fw[(lane + 64) * 4 + c];
    #pragma unroll
    for (int off = 32; off >= 1; off >>= 1)
        #pragma unroll
        for (int c = 0; c < 4; ++c) p[c] += __shfl_down(p[c], off);
    if (lane == 0) {
        #pragma unroll
        for (int c = 0; c < 4; ++c) out[(size_t)node * 4 + c] = p[c] + fb[c];
    }
}

#define CSR_INTS ((size_t)(NPP + 4) + NEDGE + (NAU + 4) + NEDGE)
#define WT_ELEMS ((size_t)10 * HD * HD)

template<bool GATHER>
static void run_all(void* const* d_in, void* d_out, void* d_ws, hipStream_t stream)
{
    const float* x_author = (const float*)d_in[0];
    const float* x_paper  = (const float*)d_in[1];
    const int*   ei_ap    = (const int*)d_in[2];
    const int*   ei_pa    = (const int*)d_in[3];
    const float* drop_a   = (const float*)d_in[4];
    const float* drop_p   = (const float*)d_in[5];
    const float* lin_a_w  = (const float*)d_in[6];
    const float* lin_a_b  = (const float*)d_in[7];
    const float* lin_p_w  = (const float*)d_in[8];
    const float* lin_p_b  = (const float*)d_in[9];
    const float* W1       = (const float*)d_in[10];
    const float* B1       = (const float*)d_in[11];
    const float* G        = (const float*)d_in[12];
    const float* BT       = (const float*)d_in[13];
    const float* W2       = (const float*)d_in[14];
    const float* B2       = (const float*)d_in[15];
    const float* EPS      = (const float*)d_in[16];
    const float* fw       = (const float*)d_in[17];
    const float* fb       = (const float*)d_in[18];

    // ws: [stats 8*HD f32 (4 sets)][Wt][CSR?][agg][proj?][h_a][h_p]
    float* stats = (float*)d_ws;                  // set t: gsum=stats+t*2*HD
    bf16r* wt = (bf16r*)(stats + 8 * HD);
    char* cp = (char*)(wt + WT_ELEMS);

    int *off_ap = nullptr, *bkt_ap = nullptr, *off_pa = nullptr, *bkt_pa = nullptr;
    if (GATHER) {
        int* ip = (int*)cp;
        off_ap = ip;  ip += NPP + 4;
        bkt_ap = ip;  ip += NEDGE;
        off_pa = ip;  ip += NAU + 4;
        bkt_pa = ip;  ip += NEDGE;
        cp = (char*)ip;
    }
    void* agg_a_v = cp;
    size_t aggElem = GATHER ? sizeof(bf16r) : sizeof(float);
    void* agg_p_v = cp + (size_t)NAU * HD * aggElem;
    cp += (size_t)(NAU + NPP) * HD * aggElem;
    bf16r* proj_a = nullptr; bf16r* proj_p = nullptr;
    if (GATHER) {
        proj_a = (bf16r*)cp;  cp += (size_t)NAU * HD * sizeof(bf16r);
        proj_p = (bf16r*)cp;  cp += (size_t)NPP * HD * sizeof(bf16r);
    }
    bf16r* h_a = (bf16r*)cp;
    bf16r* h_p = h_a + (size_t)NRUNS * NAU * HD;

    const bf16r* wt_lin_a = wt;
    const bf16r* wt_lin_p = wt + (size_t)1 * HD * HD;
    const bf16r* wt_W1    = wt + (size_t)2 * HD * HD;
    const bf16r* wt_W2    = wt + (size_t)6 * HD * HD;

    // CSR cur arrays alias agg region (dead until first gather)
    int* cur_ap = (int*)agg_a_v;
    int* cur_pa = cur_ap + NPP;
    int* partial = cur_pa + NAU;

    convw_prep_k<<<788, 256, 0, stream>>>(lin_a_w, lin_p_w, W1, W2, wt, stats,
                                          (float*)cur_ap, (NPP + NAU) / 4);

    if (GATHER) {
        count2_k<<<(2 * NEDGE + 255) / 256, 256, 0, stream>>>(ei_ap, ei_pa, cur_ap, cur_pa);
        scan1m_k<<<C_AP + C_PA, 256, 0, stream>>>(cur_ap, off_ap, cur_pa, off_pa, partial);
        scan2m_k<<<2, 256, 0, stream>>>(partial);
        scan3m_k<<<C_AP + C_PA, 256, 0, stream>>>(off_ap, cur_ap, off_pa, cur_pa, partial);
        fill2_k<<<(2 * NEDGE + 255) / 256, 256, 0, stream>>>(ei_ap, ei_pa,
                                                             cur_ap, bkt_ap, cur_pa, bkt_pa);
    }

    const int TP = NRUNS * NPP / 64, TA = NRUNS * NAU / 64;
    const int BPgin = (int)((long)NB_GEMM * TP / (TP + TA));

    if (GATHER) {
        // ---- single-copy PROJ ----
        SideP Pp = {}, Pa = {};
        Pp.in = x_paper; Pp.out = proj_p; Pp.wt = wt_lin_p; Pp.bias = lin_p_b;
        Pp.M = NPP; Pp.Nn = NPP; Pp.tiles = (NPP + 63) / 64;
        Pa.in = x_author; Pa.out = proj_a; Pa.wt = wt_lin_a; Pa.bias = lin_a_b;
        Pa.M = NAU; Pa.Nn = NAU; Pa.tiles = (NAU + 63) / 64;
        int BPproj = (int)((long)NB_GEMM * Pp.tiles / (Pp.tiles + Pa.tiles));
        mfma_gemm<M_PROJ1, float, float><<<NB_GEMM, 256, 0, stream>>>(Pp, Pa, BPproj);

        for (int l = 0; l < 2; ++l) {
            int t0 = l * 2 + 0, t1 = l * 2 + 1;

            if (l == 0) {
                gather2_k<true><<<((NPP + NAU) * 64) / 256, 256, 0, stream>>>(
                    proj_a, proj_p, (bf16r*)agg_p_v, (bf16r*)agg_a_v,
                    off_ap, bkt_ap, off_pa, bkt_pa, drop_a, drop_p);
            } else {
                gather2_k<false><<<((NPP + NAU) * 64) / 256, 256, 0, stream>>>(
                    h_a, h_p, (bf16r*)agg_p_v, (bf16r*)agg_a_v,
                    off_ap, bkt_ap, off_pa, bkt_pa, nullptr, nullptr);
            }

            SideP G1p = {}, G1a = {};
            G1p.wt = wt_W1 + (size_t)t0 * HD * HD;
            G1p.bias = B1 + (size_t)t0 * HD; G1p.epsp = EPS + t0;
            G1p.agg = agg_p_v;
            G1p.gsum = stats + t0 * 2 * HD; G1p.gsumsq = G1p.gsum + HD;
            G1p.M = NRUNS * NPP; G1p.Nn = NPP; G1p.tiles = TP; G1p.out = h_p;
            G1a.wt = wt_W1 + (size_t)t1 * HD * HD;
            G1a.bias = B1 + (size_t)t1 * HD; G1a.epsp = EPS + t1;
            G1a.agg = agg_a_v;
            G1a.gsum = stats + t1 * 2 * HD; G1a.gsumsq = G1a.gsum + HD;
            G1a.M = NRUNS * NAU; G1a.Nn = NAU; G1a.tiles = TA; G1a.out = h_a;
            if (l == 0) {
                G1p.in = proj_p; G1p.mask = drop_p;
                G1a.in = proj_a; G1a.mask = drop_a;
                mfma_gemm<M_GIN1M, bf16r, bf16r><<<NB_GEMM, 256, 0, stream>>>(G1p, G1a, BPgin);
            } else {
                G1p.in = h_p;
                G1a.in = h_a;
                mfma_gemm<M_GIN1, bf16r, bf16r><<<NB_GEMM, 256, 0, stream>>>(G1p, G1a, BPgin);
            }

            SideP G2p = {}, G2a = {};
            G2p.in = h_p; G2p.out = h_p; G2p.wt = wt_W2 + (size_t)t0 * HD * HD;
            G2p.bias = B2 + (size_t)t0 * HD;
            G2p.gsum = stats + t0 * 2 * HD; G2p.gsumsq = G2p.gsum + HD;
            G2p.gamma = G + (size_t)t0 * HD; G2p.beta = BT + (size_t)t0 * HD;
            G2p.invN = 1.0f / (NRUNS * NPP);
            G2p.M = NRUNS * NPP; G2p.Nn = NPP; G2p.tiles = TP;
            G2a.in = h_a; G2a.out = h_a; G2a.wt = wt_W2 + (size_t)t1 * HD * HD;
            G2a.bias = B2 + (size_t)t1 * HD;
            G2a.gsum = stats + t1 * 2 * HD; G2a.gsumsq = G2a.gsum + HD;
            G2a.gamma = G + (size_t)t1 * HD; G2a.beta = BT + (size_t)t1 * HD;
            G2a.invN = 1.0f / (NRUNS * NAU);
            G2a.M = NRUNS * NAU; G2a.Nn = NAU; G2a.tiles = TA;
            mfma_gemm<M_GIN2, bf16r, float><<<NB_GEMM, 256, 0, stream>>>(G2p, G2a, BPgin);
        }
    } else {
        // fallback: masked 4-copy PROJ + atomic scatter + f32 agg GIN1
        SideP Pp = {}, Pa = {};
        Pp.in = x_paper; Pp.out = h_p; Pp.wt = wt_lin_p; Pp.bias = lin_p_b;
        Pp.mask = drop_p; Pp.M = NPP; Pp.Nn = NPP; Pp.tiles = (NPP + 63) / 64;
        Pa.in = x_author; Pa.out = h_a; Pa.wt = wt_lin_a; Pa.bias = lin_a_b;
        Pa.mask = drop_a; Pa.M = NAU; Pa.Nn = NAU; Pa.tiles = (NAU + 63) / 64;
        int BPproj = (int)((long)NB_GEMM * Pp.tiles / (Pp.tiles + Pa.tiles));
        mfma_gemm<M_PROJ, float, float><<<NB_GEMM, 256, 0, stream>>>(Pp, Pa, BPproj);

        for (int l = 0; l < 2; ++l) {
            int t0 = l * 2 + 0, t1 = l * 2 + 1;
            zero_k<<<2048, 256, 0, stream>>>((float*)agg_a_v, ((size_t)(NAU + NPP) * HD) / 4);
            scatter_k<<<(NEDGE * 32) / 256, 256, 0, stream>>>(h_a, (float*)agg_p_v, ei_ap, NEDGE);
            scatter_k<<<(NEDGE * 32) / 256, 256, 0, stream>>>(h_p, (float*)agg_a_v, ei_pa, NEDGE);

            SideP G1p = {}, G1a = {};
            G1p.in = h_p; G1p.out = h_p; G1p.wt = wt_W1 + (size_t)t0 * HD * HD;
            G1p.bias = B1 + (size_t)t0 * HD; G1p.agg = agg_p_v; G1p.epsp = EPS + t0;
            G1p.gsum = stats + t0 * 2 * HD; G1p.gsumsq = G1p.gsum + HD;
            G1p.M = NRUNS * NPP; G1p.Nn = NPP; G1p.tiles = TP;
            G1a.in = h_a; G1a.out = h_a; G1a.wt = wt_W1 + (size_t)t1 * HD * HD;
            G1a.bias = B1 + (size_t)t1 * HD; G1a.agg = agg_a_v; G1a.epsp = EPS + t1;
            G1a.gsum = stats + t1 * 2 * HD; G1a.gsumsq = G1a.gsum + HD;
            G1a.M = NRUNS * NAU; G1a.Nn = NAU; G1a.tiles = TA;
            mfma_gemm<M_GIN1, bf16r, float><<<NB_GEMM, 256, 0, stream>>>(G1p, G1a, BPgin);

            SideP G2p = {}, G2a = {};
            G2p.in = h_p; G2p.out = h_p;
            G2p.wt = wt_W2 + (size_t)t0 * HD * HD; G2p.bias = B2 + (size_t)t0 * HD;
            G2p.gsum = stats + t0 * 2 * HD; G2p.gsumsq = G2p.gsum + HD;
            G2p.gamma = G + (size_t)t0 * HD; G2p.beta = BT + (size_t)t0 * HD;
            G2p.invN = 1.0f / (NRUNS * NPP);
            G2p.M = NRUNS * NPP; G2p.Nn = NPP; G2p.tiles = TP;
            G2a.in = h_a; G2a.out = h_a;
            G2a.wt = wt_W2 + (size_t)t1 * HD * HD; G2a.bias = B2 + (size_t)t1 * HD;
            G2a.gsum = stats + t1 * 2 * HD; G2a.gsumsq = G2a.gsum + HD;
            G2a.gamma = G + (size_t)t1 * HD; G2a.beta = BT + (size_t)t1 * HD;
            G2a.invN = 1.0f / (NRUNS * NAU);
            G2a.M = NRUNS * NAU; G2a.Nn = NAU; G2a.tiles = TA;
            mfma_gemm<M_GIN2, bf16r, float><<<NB_GEMM, 256, 0, stream>>>(G2p, G2a, BPgin);
        }
    }

    final_k<<<(NAU * 64) / 256, 256, 0, stream>>>(h_a, fw, fb, (float*)d_out);
}

extern "C" void kernel_launch(void* const* d_in, const int* in_sizes, int n_in,
                              void* d_out, int out_size, void* d_ws, size_t ws_size,
                              hipStream_t stream)
{
    const size_t hB    = (size_t)NRUNS * (NAU + NPP) * HD * sizeof(bf16r);
    const size_t statB = 8 * HD * sizeof(float);
    const size_t wtB   = WT_ELEMS * sizeof(bf16r);
    const size_t csrB  = CSR_INTS * sizeof(int);
    const size_t aggBF = (size_t)(NAU + NPP) * HD * sizeof(bf16r);
    const size_t projB = (size_t)(NAU + NPP) * HD * sizeof(bf16r);

    const size_t need_gather = statB + wtB + csrB + aggBF + projB + hB;  // ~235.3 MB
    if (ws_size >= need_gather) {
        run_all<true>(d_in, d_out, d_ws, stream);
    } else {
        run_all<false>(d_in, d_out, d_ws, stream);   // atomic fallback
    }
}

// Round 14
// 579.034 us; speedup vs baseline: 1.2990x; 1.0418x over previous
//
#include <hip/hip_runtime.h>

#define NRUNS 4
#define NAU 50000
#define NPP 100000
#define NEDGE 500000
#define HD 128
#define INV_KEEP 1.25f
#define BN_EPS 1e-5f
#define LDA 136      // padded LDS row (bf16 elems), 272B
#define NB_GEMM 1024 // persistent GEMM grid (512-thr blocks, 3-4/CU)

#define M_PROJ   0   // masked 4-copy projection (fallback path)
#define M_GIN1   1   // GIN stage-1 reading h + agg (layer >= 1 / fallback)
#define M_GIN2   2   // BN(from stats)+relu + W2 + relu, in place
#define M_PROJ1  3   // single-copy unmasked projection (main path)
#define M_GIN1M  4   // layer-0 GIN stage-1: input = mask*1.25*proj + agg

#define C_AP ((NPP + 1023) / 1024)   // 98 scan chunks, graph ap
#define C_PA ((NAU + 1023) / 1024)   // 49 scan chunks, graph pa

typedef unsigned short bf16r;
typedef __attribute__((ext_vector_type(8))) short v8s;   // 8 bf16 (4 VGPR)
typedef __attribute__((ext_vector_type(4))) float v4f;   // 4 f32 acc

__device__ inline float bf2f(bf16r u) {
    return __uint_as_float(((unsigned)u) << 16);
}
__device__ inline bf16r f2bf(float f) {
    __bf16 b = (__bf16)f;
    return __builtin_bit_cast(bf16r, b);
}

__global__ __launch_bounds__(256)
void zero_k(float* p, long n4) {
    long i = (long)blockIdx.x * 256 + threadIdx.x;
    long stride = (long)gridDim.x * 256;
    float4 z = make_float4(0.f, 0.f, 0.f, 0.f);
    for (; i < n4; i += stride) ((float4*)p)[i] = z;
}

// weight convert (blocks 0..639) + zero 4 stat sets (block 640) + zero CSR
// cur arrays (blocks 641..787). One dispatch.
__global__ __launch_bounds__(256)
void convw_prep_k(const float* __restrict__ lin_a_w, const float* __restrict__ lin_p_w,
                  const float* __restrict__ W1, const float* __restrict__ W2,
                  bf16r* __restrict__ wt, float* __restrict__ stats,
                  float* __restrict__ curz, int curz4)
{
    int b = blockIdx.x;
    if (b < 640) {
        int t = b >> 6;
        int e = (b & 63) * 256 + threadIdx.x;
        const float* src;
        if (t == 0) src = lin_a_w;
        else if (t == 1) src = lin_p_w;
        else if (t < 6) src = W1 + (size_t)(t - 2) * HD * HD;
        else src = W2 + (size_t)(t - 6) * HD * HD;
        int n = e >> 7, k = e & 127;
        wt[(size_t)t * HD * HD + e] = f2bf(src[(size_t)k * HD + n]);
    } else if (b == 640) {
        ((float4*)stats)[threadIdx.x] = make_float4(0.f, 0.f, 0.f, 0.f);  // 8*HD f32
    } else {
        int i = (b - 641) * 256 + threadIdx.x;
        if (i < curz4) ((float4*)curz)[i] = make_float4(0.f, 0.f, 0.f, 0.f);
    }
}

// ============ CSR build, both graphs per dispatch ============
__global__ __launch_bounds__(256)
void count2_k(const int* __restrict__ ei_ap, const int* __restrict__ ei_pa,
              int* curA, int* curB)
{
    int g = blockIdx.x * 256 + threadIdx.x;
    if (g < NEDGE) atomicAdd(&curA[ei_ap[NEDGE + g]], 1);
    else if (g < 2 * NEDGE) atomicAdd(&curB[ei_pa[NEDGE + (g - NEDGE)]], 1);
}

__global__ __launch_bounds__(256)
void scan1m_k(const int* __restrict__ curA, int* offA,
              const int* __restrict__ curB, int* offB, int* partial)
{
    __shared__ int lds[256];
    int b = blockIdx.x, t = threadIdx.x;
    const int* in; int* out; int n, chunk;
    if (b < C_AP) { in = curA; out = offA; n = NPP; chunk = b; }
    else          { in = curB; out = offB; n = NAU; chunk = b - C_AP; }
    int base = chunk * 1024 + t * 4;
    int v0 = 0, v1 = 0, v2 = 0, v3 = 0;
    if (base + 3 < n) {
        int4 x = *(const int4*)(in + base);
        v0 = x.x; v1 = x.y; v2 = x.z; v3 = x.w;
    } else {
        if (base + 0 < n) v0 = in[base + 0];
        if (base + 1 < n) v1 = in[base + 1];
        if (base + 2 < n) v2 = in[base + 2];
        if (base + 3 < n) v3 = in[base + 3];
    }
    int s = v0 + v1 + v2 + v3;
    lds[t] = s;
    __syncthreads();
    for (int d = 1; d < 256; d <<= 1) {
        int x = (t >= d) ? lds[t - d] : 0;
        __syncthreads();
        lds[t] += x;
        __syncthreads();
    }
    int excl = lds[t] - s;
    if (base + 0 < n) out[base + 0] = excl;
    if (base + 1 < n) out[base + 1] = excl + v0;
    if (base + 2 < n) out[base + 2] = excl + v0 + v1;
    if (base + 3 < n) out[base + 3] = excl + v0 + v1 + v2;
    if (t == 255) partial[b] = lds[255];
}

__global__ __launch_bounds__(256)
void scan2m_k(int* partial)
{
    __shared__ int lds[256];
    int t = threadIdx.x;
    int base = blockIdx.x == 0 ? 0 : C_AP;
    int n = blockIdx.x == 0 ? C_AP : C_PA;
    int s = (t < n) ? partial[base + t] : 0;
    lds[t] = s;
    __syncthreads();
    for (int d = 1; d < 256; d <<= 1) {
        int x = (t >= d) ? lds[t - d] : 0;
        __syncthreads();
        lds[t] += x;
        __syncthreads();
    }
    if (t < n) partial[base + t] = lds[t] - s;
}

__global__ __launch_bounds__(256)
void scan3m_k(int* offA, int* curA, int* offB, int* curB,
              const int* __restrict__ partial)
{
    int b = blockIdx.x, t = threadIdx.x;
    int* off; int* cur; int n, chunk;
    if (b < C_AP) { off = offA; cur = curA; n = NPP; chunk = b; }
    else          { off = offB; cur = curB; n = NAU; chunk = b - C_AP; }
    int add = partial[b];
    int base = chunk * 1024 + t * 4;
    #pragma unroll
    for (int j = 0; j < 4; ++j) {
        int i = base + j;
        if (i < n) {
            int v = off[i] + add;
            off[i] = v;
            cur[i] = v;
        }
    }
    if (chunk == 0 && t == 0) off[n] = NEDGE;
}

__global__ __launch_bounds__(256)
void fill2_k(const int* __restrict__ ei_ap, const int* __restrict__ ei_pa,
             int* curA, int* bktA, int* curB, int* bktB)
{
    int g = blockIdx.x * 256 + threadIdx.x;
    if (g < NEDGE) {
        int d = ei_ap[NEDGE + g];
        bktA[atomicAdd(&curA[d], 1)] = ei_ap[g];
    } else if (g < 2 * NEDGE) {
        int e = g - NEDGE;
        int d = ei_pa[NEDGE + e];
        bktB[atomicAdd(&curB[d], 1)] = ei_pa[e];
    }
}

// combined gather (both graphs), one 64-lane wave per dst node, f32 accum,
// bf16 store. MASKED: value = mask0[src]*1.25*src_row (layer 0, from proj).
template<bool MASKED>
__global__ __launch_bounds__(256)
void gather2_k(const bf16r* __restrict__ hA, const bf16r* __restrict__ hP,
               bf16r* __restrict__ aggP, bf16r* __restrict__ aggA,
               const int* __restrict__ offAP, const int* __restrict__ bktAP,
               const int* __restrict__ offPA, const int* __restrict__ bktPA,
               const float* __restrict__ mA0, const float* __restrict__ mP0)
{
    int gw = (blockIdx.x * 256 + threadIdx.x) >> 6;
    int lane = threadIdx.x & 63;
    const bf16r* src; bf16r* agg; const int* off; const int* bkt;
    const float* msk; int w;
    if (gw < NPP) { src = hA; agg = aggP; off = offAP; bkt = bktAP; msk = mA0; w = gw; }
    else          { src = hP; agg = aggA; off = offPA; bkt = bktPA; msk = mP0; w = gw - NPP; }
    int s0 = off[w], s1 = off[w + 1];
    float a0 = 0.f, a1 = 0.f;
    int e = s0;
    for (; e + 1 < s1; e += 2) {
        int i0 = bkt[e], i1 = bkt[e + 1];
        ushort2 u = *(const ushort2*)(src + (size_t)i0 * HD + lane * 2);
        ushort2 v = *(const ushort2*)(src + (size_t)i1 * HD + lane * 2);
        if constexpr (MASKED) {
            float m0 = msk[i0] * INV_KEEP, m1 = msk[i1] * INV_KEEP;
            a0 += m0 * bf2f(u.x) + m1 * bf2f(v.x);
            a1 += m0 * bf2f(u.y) + m1 * bf2f(v.y);
        } else {
            a0 += bf2f(u.x) + bf2f(v.x);
            a1 += bf2f(u.y) + bf2f(v.y);
        }
    }
    if (e < s1) {
        int i0 = bkt[e];
        ushort2 u = *(const ushort2*)(src + (size_t)i0 * HD + lane * 2);
        float m0 = MASKED ? msk[i0] * INV_KEEP : 1.0f;
        a0 += m0 * bf2f(u.x);
        a1 += m0 * bf2f(u.y);
    }
    ushort2 o;
    o.x = f2bf(a0);
    o.y = f2bf(a1);
    *(ushort2*)(agg + (size_t)w * HD + lane * 2) = o;
}

// fallback scatter (atomics, f32 agg)
__global__ __launch_bounds__(256)
void scatter_k(const bf16r* __restrict__ src, float* dst,
               const int* __restrict__ ei, int E)
{
    int g = blockIdx.x * 256 + threadIdx.x;
    int e = g >> 5, lane = g & 31;
    if (e >= E) return;
    int s = ei[e], d = ei[E + e];
    ushort4 u = *(const ushort4*)(src + (size_t)s * HD + lane * 4);
    float* dp = dst + (size_t)d * HD + lane * 4;
    unsafeAtomicAdd(dp + 0, bf2f(u.x));
    unsafeAtomicAdd(dp + 1, bf2f(u.y));
    unsafeAtomicAdd(dp + 2, bf2f(u.z));
    unsafeAtomicAdd(dp + 3, bf2f(u.w));
}

// ================= persistent pipelined MFMA GEMM (512 threads) =================
struct SideP {
    const void* in;       // self input (proj for GIN1M [node-idx], h otherwise)
    bf16r* out;
    const void* agg;      // AT-typed (bf16 main, f32 fallback)
    const bf16r* wt;
    const float* bias;
    const float* epsp;
    float* gsum;
    float* gsumsq;
    const float* gamma;   // GIN2
    const float* beta;    // GIN2
    float invN;           // GIN2
    const float* mask;    // PROJ: [R][Nn]; GIN1M: flat [R*Nn]
    int M, Nn, tiles;
};

// 512-thread blocks: 8 waves, each wave owns a 16-col band (1 col-frag x
// 4 row-frags) -> per-thread state halves vs the 256-thr version (w 16,
// acc 16, prefetch 8+8 VGPR) -> target 6-8 waves/SIMD residency (24-32
// waves/CU vs 20 at VGPR=92). Single-buffered LDS A-tile, 2-barrier
// schedule, register prefetch of h AND agg. GIN1* accumulate BN stats in
// regs; GIN2 derives BN scale/shift from stats in-kernel.
template<int MODE, typename IT, typename AT>
__global__ __launch_bounds__(512)
void mfma_gemm(SideP P, SideP A, int BP)
{
    __shared__ bf16r za[64][LDA];
    __shared__ float red[2][HD];
    const int tid = threadIdx.x;

    SideP S;
    int t, tstride;
    if ((int)blockIdx.x < BP) { S = P; t = blockIdx.x; tstride = BP; }
    else { S = A; t = (int)blockIdx.x - BP; tstride = NB_GEMM - BP; }
    if (t >= S.tiles) return;

    constexpr bool GIN1ANY = (MODE == M_GIN1 || MODE == M_GIN1M);
    constexpr bool PMSK    = (MODE == M_GIN1M);
    constexpr int  NVH     = (MODE == M_PROJ || MODE == M_PROJ1) ? 2 : 1;
    constexpr int  NVA     = (GIN1ANY && sizeof(AT) == 4) ? 2 : 1;

    const int wid = tid >> 6, lane = tid & 63;
    const int lr = lane & 15, lk = (lane >> 4) * 8;
    const int colq = (lane >> 4) * 4;
    const int cb = wid * 16;            // wave's 16-col band
    const int srow = tid >> 4;          // 0..31; chunk i adds 32
    const int scol = (tid & 15) * 8;

    float epsv = 1.0f;
    if (GIN1ANY) epsv = 1.0f + S.epsp[0];

    v8s w[4];
    #pragma unroll
    for (int ks = 0; ks < 4; ++ks)
        w[ks] = *(const v8s*)(S.wt + (size_t)(cb + lr) * HD + ks * 32 + lk);

    const float4 bb = *(const float4*)(S.bias + cb + colq);

    // GIN2: per-thread BN scale/shift for this thread's 8 staging cols
    float sc8[MODE == M_GIN2 ? 8 : 1], sh8[MODE == M_GIN2 ? 8 : 1];
    if constexpr (MODE == M_GIN2) {
        #pragma unroll
        for (int j = 0; j < 8; ++j) {
            int c = scol + j;
            float mu = S.gsum[c] * S.invN;
            float var = S.gsumsq[c] * S.invN - mu * mu;
            float s = S.gamma[c] * rsqrtf(var + BN_EPS);
            sc8[j] = s;
            sh8[j] = S.beta[c] - mu * s;
        }
    }

    float st_s[4], st_q[4];
    if (GIN1ANY) {
        #pragma unroll
        for (int j = 0; j < 4; ++j) { st_s[j] = 0.f; st_q[j] = 0.f; }
    }

    int4 pre[2][NVH];
    int4 preA[2][NVA];
    float mpre[PMSK ? 2 : 1];

    auto prefetch = [&](int tt) {
        int m0n = tt * 64;
        #pragma unroll
        for (int i = 0; i < 2; ++i) {
            int gr = m0n + srow + 32 * i;
            if constexpr (PMSK) {
                // per-row run (Nn not 64-divisible)
                int run = (gr >= S.Nn) + (gr >= 2 * S.Nn) + (gr >= 3 * S.Nn);
                int node = gr - run * S.Nn;
                mpre[i] = S.mask[gr];
                pre[i][0] = *(const int4*)((const bf16r*)S.in + (size_t)node * HD + scol);
            } else if (gr < S.M) {
                const int4* p = (const int4*)((const IT*)S.in + (size_t)gr * HD + scol);
                pre[i][0] = p[0];
                if constexpr (NVH == 2) pre[i][1] = p[1];
            } else {
                pre[i][0] = make_int4(0, 0, 0, 0);
                if constexpr (NVH == 2) pre[i][1] = make_int4(0, 0, 0, 0);
            }
            if constexpr (GIN1ANY) {
                if (gr < S.Nn) {
                    const int4* pa = (const int4*)((const AT*)S.agg + (size_t)gr * HD + scol);
                    preA[i][0] = pa[0];
                    if constexpr (NVA == 2) preA[i][1] = pa[1];
                } else {
                    preA[i][0] = make_int4(0, 0, 0, 0);
                    if constexpr (NVA == 2) preA[i][1] = make_int4(0, 0, 0, 0);
                }
            }
        }
    };

    prefetch(t);

    for (;;) {
        const int m0 = t * 64;
        // ---- stage ----
        #pragma unroll
        for (int i = 0; i < 2; ++i) {
            int row = srow + 32 * i;
            float v[8];
            if constexpr (NVH == 2) {
                const float* pf = (const float*)&pre[i][0];
                #pragma unroll
                for (int j = 0; j < 8; ++j) v[j] = pf[j];
            } else {
                const bf16r* pu = (const bf16r*)&pre[i][0];
                #pragma unroll
                for (int j = 0; j < 8; ++j) v[j] = bf2f(pu[j]);
            }
            if constexpr (GIN1ANY) {
                float av[8];
                if constexpr (sizeof(AT) == 4) {
                    const float* pa = (const float*)&preA[i][0];
                    #pragma unroll
                    for (int j = 0; j < 8; ++j) av[j] = pa[j];
                } else {
                    const bf16r* pa = (const bf16r*)&preA[i][0];
                    #pragma unroll
                    for (int j = 0; j < 8; ++j) av[j] = bf2f(pa[j]);
                }
                float coef = epsv;
                if constexpr (PMSK) coef = mpre[i] * INV_KEEP * epsv;
                #pragma unroll
                for (int j = 0; j < 8; ++j) v[j] = v[j] * coef + av[j];
            } else if constexpr (MODE == M_GIN2) {
                #pragma unroll
                for (int j = 0; j < 8; ++j)
                    v[j] = fmaxf(v[j] * sc8[j] + sh8[j], 0.f);
            }
            union { v8s w8; bf16r u[8]; } pk;
            #pragma unroll
            for (int j = 0; j < 8; ++j) pk.u[j] = f2bf(v[j]);
            *(v8s*)&za[row][scol] = pk.w8;
        }
        __syncthreads();

        // ---- prefetch next tile (stays in flight under compute) ----
        const int tn = t + tstride;
        const bool more = tn < S.tiles;
        if (more) prefetch(tn);

        // ---- compute: wave's 16-col band x 64 rows ----
        v4f acc[4];
        #pragma unroll
        for (int rf = 0; rf < 4; ++rf) acc[rf] = (v4f){0.f, 0.f, 0.f, 0.f};

        #pragma unroll
        for (int ks = 0; ks < 4; ++ks)
            #pragma unroll
            for (int rf = 0; rf < 4; ++rf) {
                v8s a = *(const v8s*)&za[rf * 16 + lr][ks * 32 + lk];
                acc[rf] = __builtin_amdgcn_mfma_f32_16x16x32_bf16(w[ks], a, acc[rf], 0, 0, 0);
            }

        #pragma unroll
        for (int rf = 0; rf < 4; ++rf) {
            acc[rf][0] += bb.x; acc[rf][1] += bb.y;
            acc[rf][2] += bb.z; acc[rf][3] += bb.w;
        }

        if constexpr (MODE == M_PROJ) {
            #pragma unroll
            for (int rf = 0; rf < 4; ++rf) {
                int grow = m0 + rf * 16 + lr;
                if (grow < S.M) {
                    #pragma unroll
                    for (int run = 0; run < NRUNS; ++run) {
                        float wm = S.mask[(size_t)run * S.Nn + grow] * INV_KEEP;
                        ushort4 o;
                        o.x = f2bf(acc[rf][0] * wm);
                        o.y = f2bf(acc[rf][1] * wm);
                        o.z = f2bf(acc[rf][2] * wm);
                        o.w = f2bf(acc[rf][3] * wm);
                        *(ushort4*)(S.out + ((size_t)run * S.Nn + grow) * HD + cb + colq) = o;
                    }
                }
            }
        } else if constexpr (MODE == M_PROJ1) {
            #pragma unroll
            for (int rf = 0; rf < 4; ++rf) {
                int grow = m0 + rf * 16 + lr;
                if (grow < S.M) {
                    ushort4 o;
                    o.x = f2bf(acc[rf][0]);
                    o.y = f2bf(acc[rf][1]);
                    o.z = f2bf(acc[rf][2]);
                    o.w = f2bf(acc[rf][3]);
                    *(ushort4*)(S.out + (size_t)grow * HD + cb + colq) = o;
                }
            }
        } else if constexpr (GIN1ANY) {
            #pragma unroll
            for (int rf = 0; rf < 4; ++rf) {
                int grow = m0 + rf * 16 + lr;
                ushort4 o;
                o.x = f2bf(acc[rf][0]);
                o.y = f2bf(acc[rf][1]);
                o.z = f2bf(acc[rf][2]);
                o.w = f2bf(acc[rf][3]);
                *(ushort4*)(S.out + (size_t)grow * HD + cb + colq) = o;
            }
            #pragma unroll
            for (int j = 0; j < 4; ++j)
                #pragma unroll
                for (int rf = 0; rf < 4; ++rf) {
                    float vv = acc[rf][j];
                    st_s[j] += vv;
                    st_q[j] += vv * vv;
                }
        } else {  // M_GIN2
            #pragma unroll
            for (int rf = 0; rf < 4; ++rf) {
                int grow = m0 + rf * 16 + lr;
                ushort4 o;
                o.x = f2bf(fmaxf(acc[rf][0], 0.f));
                o.y = f2bf(fmaxf(acc[rf][1], 0.f));
                o.z = f2bf(fmaxf(acc[rf][2], 0.f));
                o.w = f2bf(fmaxf(acc[rf][3], 0.f));
                *(ushort4*)(S.out + (size_t)grow * HD + cb + colq) = o;
            }
        }

        if (!more) break;
        t = tn;
        __syncthreads();
    }

    if constexpr (GIN1ANY) {
        // reduce stats over the 16 lr lanes of each 16-lane group
        #pragma unroll
        for (int d = 1; d < 16; d <<= 1)
            #pragma unroll
            for (int j = 0; j < 4; ++j) {
                st_s[j] += __shfl_xor(st_s[j], d);
                st_q[j] += __shfl_xor(st_q[j], d);
            }
        if (lr == 0) {
            #pragma unroll
            for (int j = 0; j < 4; ++j) {
                red[0][cb + colq + j] = st_s[j];
                red[1][cb + colq + j] = st_q[j];
            }
        }
        __syncthreads();
        if (tid < HD) {
            unsafeAtomicAdd(S.gsum + tid, red[0][tid]);
            unsafeAtomicAdd(S.gsumsq + tid, red[1][tid]);
        }
    }
}

// mean over runs + [128]x[128,4] matmul
__global__ __launch_bounds__(256)
void final_k(const bf16r* __restrict__ ha, const float* __restrict__ fw,
             const float* __restrict__ fb, float* __restrict__ out)
{
    int g = blockIdx.x * 256 + threadIdx.x;
    int node = g >> 6, lane = g & 63;
    if (node >= NAU) return;
    float m0 = 0.f, m1 = 0.f;
    #pragma unroll
    for (int r = 0; r < NRUNS; ++r) {
        size_t base = ((size_t)r * NAU + node) * HD;
        m0 += bf2f(ha[base + lane]);
        m1 += bf2f(ha[base + 64 + lane]);
    }
    m0 *= 0.25f;
    m1 *= 0.25f;
    float p[4];
    #pragma unroll
    for (int c = 0; c < 4; ++c)
        p[c] = m0 * fw[lane * 4 + c] + m1 * fw[(lane + 64) * 4 + c];
    #pragma unroll
    for (int off = 32; off >= 1; off >>= 1)
        #pragma unroll
        for (int c = 0; c < 4; ++c) p[c] += __shfl_down(p[c], off);
    if (lane == 0) {
        #pragma unroll
        for (int c = 0; c < 4; ++c) out[(size_t)node * 4 + c] = p[c] + fb[c];
    }
}

#define CSR_INTS ((size_t)(NPP + 4) + NEDGE + (NAU + 4) + NEDGE)
#define WT_ELEMS ((size_t)10 * HD * HD)

template<bool GATHER>
static void run_all(void* const* d_in, void* d_out, void* d_ws, hipStream_t stream)
{
    const float* x_author = (const float*)d_in[0];
    const float* x_paper  = (const float*)d_in[1];
    const int*   ei_ap    = (const int*)d_in[2];
    const int*   ei_pa    = (const int*)d_in[3];
    const float* drop_a   = (const float*)d_in[4];
    const float* drop_p   = (const float*)d_in[5];
    const float* lin_a_w  = (const float*)d_in[6];
    const float* lin_a_b  = (const float*)d_in[7];
    const float* lin_p_w  = (const float*)d_in[8];
    const float* lin_p_b  = (const float*)d_in[9];
    const float* W1       = (const float*)d_in[10];
    const float* B1       = (const float*)d_in[11];
    const float* G        = (const float*)d_in[12];
    const float* BT       = (const float*)d_in[13];
    const float* W2       = (const float*)d_in[14];
    const float* B2       = (const float*)d_in[15];
    const float* EPS      = (const float*)d_in[16];
    const float* fw       = (const float*)d_in[17];
    const float* fb       = (const float*)d_in[18];

    // ws: [stats 8*HD f32 (4 sets)][Wt][CSR?][agg][proj?][h_a][h_p]
    float* stats = (float*)d_ws;                  // set t: gsum=stats+t*2*HD
    bf16r* wt = (bf16r*)(stats + 8 * HD);
    char* cp = (char*)(wt + WT_ELEMS);

    int *off_ap = nullptr, *bkt_ap = nullptr, *off_pa = nullptr, *bkt_pa = nullptr;
    if (GATHER) {
        int* ip = (int*)cp;
        off_ap = ip;  ip += NPP + 4;
        bkt_ap = ip;  ip += NEDGE;
        off_pa = ip;  ip += NAU + 4;
        bkt_pa = ip;  ip += NEDGE;
        cp = (char*)ip;
    }
    void* agg_a_v = cp;
    size_t aggElem = GATHER ? sizeof(bf16r) : sizeof(float);
    void* agg_p_v = cp + (size_t)NAU * HD * aggElem;
    cp += (size_t)(NAU + NPP) * HD * aggElem;
    bf16r* proj_a = nullptr; bf16r* proj_p = nullptr;
    if (GATHER) {
        proj_a = (bf16r*)cp;  cp += (size_t)NAU * HD * sizeof(bf16r);
        proj_p = (bf16r*)cp;  cp += (size_t)NPP * HD * sizeof(bf16r);
    }
    bf16r* h_a = (bf16r*)cp;
    bf16r* h_p = h_a + (size_t)NRUNS * NAU * HD;

    const bf16r* wt_lin_a = wt;
    const bf16r* wt_lin_p = wt + (size_t)1 * HD * HD;
    const bf16r* wt_W1    = wt + (size_t)2 * HD * HD;
    const bf16r* wt_W2    = wt + (size_t)6 * HD * HD;

    // CSR cur arrays alias agg region (dead until first gather)
    int* cur_ap = (int*)agg_a_v;
    int* cur_pa = cur_ap + NPP;
    int* partial = cur_pa + NAU;

    convw_prep_k<<<788, 256, 0, stream>>>(lin_a_w, lin_p_w, W1, W2, wt, stats,
                                          (float*)cur_ap, (NPP + NAU) / 4);

    if (GATHER) {
        count2_k<<<(2 * NEDGE + 255) / 256, 256, 0, stream>>>(ei_ap, ei_pa, cur_ap, cur_pa);
        scan1m_k<<<C_AP + C_PA, 256, 0, stream>>>(cur_ap, off_ap, cur_pa, off_pa, partial);
        scan2m_k<<<2, 256, 0, stream>>>(partial);
        scan3m_k<<<C_AP + C_PA, 256, 0, stream>>>(off_ap, cur_ap, off_pa, cur_pa, partial);
        fill2_k<<<(2 * NEDGE + 255) / 256, 256, 0, stream>>>(ei_ap, ei_pa,
                                                             cur_ap, bkt_ap, cur_pa, bkt_pa);
    }

    const int TP = NRUNS * NPP / 64, TA = NRUNS * NAU / 64;
    const int BPgin = (int)((long)NB_GEMM * TP / (TP + TA));

    if (GATHER) {
        // ---- single-copy PROJ ----
        SideP Pp = {}, Pa = {};
        Pp.in = x_paper; Pp.out = proj_p; Pp.wt = wt_lin_p; Pp.bias = lin_p_b;
        Pp.M = NPP; Pp.Nn = NPP; Pp.tiles = (NPP + 63) / 64;
        Pa.in = x_author; Pa.out = proj_a; Pa.wt = wt_lin_a; Pa.bias = lin_a_b;
        Pa.M = NAU; Pa.Nn = NAU; Pa.tiles = (NAU + 63) / 64;
        int BPproj = (int)((long)NB_GEMM * Pp.tiles / (Pp.tiles + Pa.tiles));
        mfma_gemm<M_PROJ1, float, float><<<NB_GEMM, 512, 0, stream>>>(Pp, Pa, BPproj);

        for (int l = 0; l < 2; ++l) {
            int t0 = l * 2 + 0, t1 = l * 2 + 1;

            if (l == 0) {
                gather2_k<true><<<((NPP + NAU) * 64) / 256, 256, 0, stream>>>(
                    proj_a, proj_p, (bf16r*)agg_p_v, (bf16r*)agg_a_v,
                    off_ap, bkt_ap, off_pa, bkt_pa, drop_a, drop_p);
            } else {
                gather2_k<false><<<((NPP + NAU) * 64) / 256, 256, 0, stream>>>(
                    h_a, h_p, (bf16r*)agg_p_v, (bf16r*)agg_a_v,
                    off_ap, bkt_ap, off_pa, bkt_pa, nullptr, nullptr);
            }

            SideP G1p = {}, G1a = {};
            G1p.wt = wt_W1 + (size_t)t0 * HD * HD;
            G1p.bias = B1 + (size_t)t0 * HD; G1p.epsp = EPS + t0;
            G1p.agg = agg_p_v;
            G1p.gsum = stats + t0 * 2 * HD; G1p.gsumsq = G1p.gsum + HD;
            G1p.M = NRUNS * NPP; G1p.Nn = NPP; G1p.tiles = TP; G1p.out = h_p;
            G1a.wt = wt_W1 + (size_t)t1 * HD * HD;
            G1a.bias = B1 + (size_t)t1 * HD; G1a.epsp = EPS + t1;
            G1a.agg = agg_a_v;
            G1a.gsum = stats + t1 * 2 * HD; G1a.gsumsq = G1a.gsum + HD;
            G1a.M = NRUNS * NAU; G1a.Nn = NAU; G1a.tiles = TA; G1a.out = h_a;
            if (l == 0) {
                G1p.in = proj_p; G1p.mask = drop_p;
                G1a.in = proj_a; G1a.mask = drop_a;
                mfma_gemm<M_GIN1M, bf16r, bf16r><<<NB_GEMM, 512, 0, stream>>>(G1p, G1a, BPgin);
            } else {
                G1p.in = h_p;
                G1a.in = h_a;
                mfma_gemm<M_GIN1, bf16r, bf16r><<<NB_GEMM, 512, 0, stream>>>(G1p, G1a, BPgin);
            }

            SideP G2p = {}, G2a = {};
            G2p.in = h_p; G2p.out = h_p; G2p.wt = wt_W2 + (size_t)t0 * HD * HD;
            G2p.bias = B2 + (size_t)t0 * HD;
            G2p.gsum = stats + t0 * 2 * HD; G2p.gsumsq = G2p.gsum + HD;
            G2p.gamma = G + (size_t)t0 * HD; G2p.beta = BT + (size_t)t0 * HD;
            G2p.invN = 1.0f / (NRUNS * NPP);
            G2p.M = NRUNS * NPP; G2p.Nn = NPP; G2p.tiles = TP;
            G2a.in = h_a; G2a.out = h_a; G2a.wt = wt_W2 + (size_t)t1 * HD * HD;
            G2a.bias = B2 + (size_t)t1 * HD;
            G2a.gsum = stats + t1 * 2 * HD; G2a.gsumsq = G2a.gsum + HD;
            G2a.gamma = G + (size_t)t1 * HD; G2a.beta = BT + (size_t)t1 * HD;
            G2a.invN = 1.0f / (NRUNS * NAU);
            G2a.M = NRUNS * NAU; G2a.Nn = NAU; G2a.tiles = TA;
            mfma_gemm<M_GIN2, bf16r, float><<<NB_GEMM, 512, 0, stream>>>(G2p, G2a, BPgin);
        }
    } else {
        // fallback: masked 4-copy PROJ + atomic scatter + f32 agg GIN1
        SideP Pp = {}, Pa = {};
        Pp.in = x_paper; Pp.out = h_p; Pp.wt = wt_lin_p; Pp.bias = lin_p_b;
        Pp.mask = drop_p; Pp.M = NPP; Pp.Nn = NPP; Pp.tiles = (NPP + 63) / 64;
        Pa.in = x_author; Pa.out = h_a; Pa.wt = wt_lin_a; Pa.bias = lin_a_b;
        Pa.mask = drop_a; Pa.M = NAU; Pa.Nn = NAU; Pa.tiles = (NAU + 63) / 64;
        int BPproj = (int)((long)NB_GEMM * Pp.tiles / (Pp.tiles + Pa.tiles));
        mfma_gemm<M_PROJ, float, float><<<NB_GEMM, 512, 0, stream>>>(Pp, Pa, BPproj);

        for (int l = 0; l < 2; ++l) {
            int t0 = l * 2 + 0, t1 = l * 2 + 1;
            zero_k<<<2048, 256, 0, stream>>>((float*)agg_a_v, ((size_t)(NAU + NPP) * HD) / 4);
            scatter_k<<<(NEDGE * 32) / 256, 256, 0, stream>>>(h_a, (float*)agg_p_v, ei_ap, NEDGE);
            scatter_k<<<(NEDGE * 32) / 256, 256, 0, stream>>>(h_p, (float*)agg_a_v, ei_pa, NEDGE);

            SideP G1p = {}, G1a = {};
            G1p.in = h_p; G1p.out = h_p; G1p.wt = wt_W1 + (size_t)t0 * HD * HD;
            G1p.bias = B1 + (size_t)t0 * HD; G1p.agg = agg_p_v; G1p.epsp = EPS + t0;
            G1p.gsum = stats + t0 * 2 * HD; G1p.gsumsq = G1p.gsum + HD;
            G1p.M = NRUNS * NPP; G1p.Nn = NPP; G1p.tiles = TP;
            G1a.in = h_a; G1a.out = h_a; G1a.wt = wt_W1 + (size_t)t1 * HD * HD;
            G1a.bias = B1 + (size_t)t1 * HD; G1a.agg = agg_a_v; G1a.epsp = EPS + t1;
            G1a.gsum = stats + t1 * 2 * HD; G1a.gsumsq = G1a.gsum + HD;
            G1a.M = NRUNS * NAU; G1a.Nn = NAU; G1a.tiles = TA;
            mfma_gemm<M_GIN1, bf16r, float><<<NB_GEMM, 512, 0, stream>>>(G1p, G1a, BPgin);

            SideP G2p = {}, G2a = {};
            G2p.in = h_p; G2p.out = h_p;
            G2p.wt = wt_W2 + (size_t)t0 * HD * HD; G2p.bias = B2 + (size_t)t0 * HD;
            G2p.gsum = stats + t0 * 2 * HD; G2p.gsumsq = G2p.gsum + HD;
            G2p.gamma = G + (size_t)t0 * HD; G2p.beta = BT + (size_t)t0 * HD;
            G2p.invN = 1.0f / (NRUNS * NPP);
            G2p.M = NRUNS * NPP; G2p.Nn = NPP; G2p.tiles = TP;
            G2a.in = h_a; G2a.out = h_a;
            G2a.wt = wt_W2 + (size_t)t1 * HD * HD; G2a.bias = B2 + (size_t)t1 * HD;
            G2a.gsum = stats + t1 * 2 * HD; G2a.gsumsq = G2a.gsum + HD;
            G2a.gamma = G + (size_t)t1 * HD; G2a.beta = BT + (size_t)t1 * HD;
            G2a.invN = 1.0f / (NRUNS * NAU);
            G2a.M = NRUNS * NAU; G2a.Nn = NAU; G2a.tiles = TA;
            mfma_gemm<M_GIN2, bf16r, float><<<NB_GEMM, 512, 0, stream>>>(G2p, G2a, BPgin);
        }
    }

    final_k<<<(NAU * 64) / 256, 256, 0, stream>>>(h_a, fw, fb, (float*)d_out);
}

extern "C" void kernel_launch(void* const* d_in, const int* in_sizes, int n_in,
                              void* d_out, int out_size, void* d_ws, size_t ws_size,
                              hipStream_t stream)
{
    const size_t hB    = (size_t)NRUNS * (NAU + NPP) * HD * sizeof(bf16r);
    const size_t statB = 8 * HD * sizeof(float);
    const size_t wtB   = WT_ELEMS * sizeof(bf16r);
    const size_t csrB  = CSR_INTS * sizeof(int);
    const size_t aggBF = (size_t)(NAU + NPP) * HD * sizeof(bf16r);
    const size_t projB = (size_t)(NAU + NPP) * HD * sizeof(bf16r);

    const size_t need_gather = statB + wtB + csrB + aggBF + projB + hB;  // ~235.3 MB
    if (ws_size >= need_gather) {
        run_all<true>(d_in, d_out, d_ws, stream);
    } else {
        run_all<false>(d_in, d_out, d_ws, stream);   // atomic fallback
    }
}

// Round 15
// 563.502 us; speedup vs baseline: 1.3348x; 1.0276x over previous
//
#include <hip/hip_runtime.h>

#define NRUNS 4
#define NAU 50000
#define NPP 100000
#define NEDGE 500000
#define HD 128
#define INV_KEEP 1.25f
#define BN_EPS 1e-5f
#define LDA 136      // padded LDS row (bf16 elems), 272B
#define NB_GEMM 1024 // persistent GEMM grid (512-thr blocks, 4/CU)

#define M_PROJ   0   // masked 4-copy projection (fallback path)
#define M_GIN1   1   // GIN stage-1 reading h + agg (layer >= 1 / fallback)
#define M_GIN2   2   // BN(from stats)+relu + W2 + relu, in place
#define M_PROJ1  3   // single-copy unmasked projection (main path)
#define M_GIN1M  4   // layer-0 GIN stage-1: input = mask*1.25*proj + agg

#define C_AP ((NPP + 1023) / 1024)   // 98 scan chunks, graph ap
#define C_PA ((NAU + 1023) / 1024)   // 49 scan chunks, graph pa

typedef unsigned short bf16r;
typedef __attribute__((ext_vector_type(8))) short v8s;   // 8 bf16 (4 VGPR)
typedef __attribute__((ext_vector_type(4))) float v4f;   // 4 f32 acc

__device__ inline float bf2f(bf16r u) {
    return __uint_as_float(((unsigned)u) << 16);
}
__device__ inline bf16r f2bf(float f) {
    __bf16 b = (__bf16)f;
    return __builtin_bit_cast(bf16r, b);
}

__global__ __launch_bounds__(256)
void zero_k(float* p, long n4) {
    long i = (long)blockIdx.x * 256 + threadIdx.x;
    long stride = (long)gridDim.x * 256;
    float4 z = make_float4(0.f, 0.f, 0.f, 0.f);
    for (; i < n4; i += stride) ((float4*)p)[i] = z;
}

// weight convert (blocks 0..639) + zero 4 stat sets (block 640) + zero CSR
// cur arrays (blocks 641..787). One dispatch.
__global__ __launch_bounds__(256)
void convw_prep_k(const float* __restrict__ lin_a_w, const float* __restrict__ lin_p_w,
                  const float* __restrict__ W1, const float* __restrict__ W2,
                  bf16r* __restrict__ wt, float* __restrict__ stats,
                  float* __restrict__ curz, int curz4)
{
    int b = blockIdx.x;
    if (b < 640) {
        int t = b >> 6;
        int e = (b & 63) * 256 + threadIdx.x;
        const float* src;
        if (t == 0) src = lin_a_w;
        else if (t == 1) src = lin_p_w;
        else if (t < 6) src = W1 + (size_t)(t - 2) * HD * HD;
        else src = W2 + (size_t)(t - 6) * HD * HD;
        int n = e >> 7, k = e & 127;
        wt[(size_t)t * HD * HD + e] = f2bf(src[(size_t)k * HD + n]);
    } else if (b == 640) {
        ((float4*)stats)[threadIdx.x] = make_float4(0.f, 0.f, 0.f, 0.f);  // 8*HD f32
    } else {
        int i = (b - 641) * 256 + threadIdx.x;
        if (i < curz4) ((float4*)curz)[i] = make_float4(0.f, 0.f, 0.f, 0.f);
    }
}

// ============ CSR build, both graphs per dispatch ============
__global__ __launch_bounds__(256)
void count2_k(const int* __restrict__ ei_ap, const int* __restrict__ ei_pa,
              int* curA, int* curB)
{
    int g = blockIdx.x * 256 + threadIdx.x;
    if (g < NEDGE) atomicAdd(&curA[ei_ap[NEDGE + g]], 1);
    else if (g < 2 * NEDGE) atomicAdd(&curB[ei_pa[NEDGE + (g - NEDGE)]], 1);
}

__global__ __launch_bounds__(256)
void scan1m_k(const int* __restrict__ curA, int* offA,
              const int* __restrict__ curB, int* offB, int* partial)
{
    __shared__ int lds[256];
    int b = blockIdx.x, t = threadIdx.x;
    const int* in; int* out; int n, chunk;
    if (b < C_AP) { in = curA; out = offA; n = NPP; chunk = b; }
    else          { in = curB; out = offB; n = NAU; chunk = b - C_AP; }
    int base = chunk * 1024 + t * 4;
    int v0 = 0, v1 = 0, v2 = 0, v3 = 0;
    if (base + 3 < n) {
        int4 x = *(const int4*)(in + base);
        v0 = x.x; v1 = x.y; v2 = x.z; v3 = x.w;
    } else {
        if (base + 0 < n) v0 = in[base + 0];
        if (base + 1 < n) v1 = in[base + 1];
        if (base + 2 < n) v2 = in[base + 2];
        if (base + 3 < n) v3 = in[base + 3];
    }
    int s = v0 + v1 + v2 + v3;
    lds[t] = s;
    __syncthreads();
    for (int d = 1; d < 256; d <<= 1) {
        int x = (t >= d) ? lds[t - d] : 0;
        __syncthreads();
        lds[t] += x;
        __syncthreads();
    }
    int excl = lds[t] - s;
    if (base + 0 < n) out[base + 0] = excl;
    if (base + 1 < n) out[base + 1] = excl + v0;
    if (base + 2 < n) out[base + 2] = excl + v0 + v1;
    if (base + 3 < n) out[base + 3] = excl + v0 + v1 + v2;
    if (t == 255) partial[b] = lds[255];
}

__global__ __launch_bounds__(256)
void scan2m_k(int* partial)
{
    __shared__ int lds[256];
    int t = threadIdx.x;
    int base = blockIdx.x == 0 ? 0 : C_AP;
    int n = blockIdx.x == 0 ? C_AP : C_PA;
    int s = (t < n) ? partial[base + t] : 0;
    lds[t] = s;
    __syncthreads();
    for (int d = 1; d < 256; d <<= 1) {
        int x = (t >= d) ? lds[t - d] : 0;
        __syncthreads();
        lds[t] += x;
        __syncthreads();
    }
    if (t < n) partial[base + t] = lds[t] - s;
}

__global__ __launch_bounds__(256)
void scan3m_k(int* offA, int* curA, int* offB, int* curB,
              const int* __restrict__ partial)
{
    int b = blockIdx.x, t = threadIdx.x;
    int* off; int* cur; int n, chunk;
    if (b < C_AP) { off = offA; cur = curA; n = NPP; chunk = b; }
    else          { off = offB; cur = curB; n = NAU; chunk = b - C_AP; }
    int add = partial[b];
    int base = chunk * 1024 + t * 4;
    #pragma unroll
    for (int j = 0; j < 4; ++j) {
        int i = base + j;
        if (i < n) {
            int v = off[i] + add;
            off[i] = v;
            cur[i] = v;
        }
    }
    if (chunk == 0 && t == 0) off[n] = NEDGE;
}

__global__ __launch_bounds__(256)
void fill2_k(const int* __restrict__ ei_ap, const int* __restrict__ ei_pa,
             int* curA, int* bktA, int* curB, int* bktB)
{
    int g = blockIdx.x * 256 + threadIdx.x;
    if (g < NEDGE) {
        int d = ei_ap[NEDGE + g];
        bktA[atomicAdd(&curA[d], 1)] = ei_ap[g];
    } else if (g < 2 * NEDGE) {
        int e = g - NEDGE;
        int d = ei_pa[NEDGE + e];
        bktB[atomicAdd(&curB[d], 1)] = ei_pa[e];
    }
}

// combined gather (both graphs), one 64-lane wave per dst node, f32 accum,
// bf16 store. Unroll-4 with split accumulators: 4 independent row loads in
// flight per iteration (the 2-deep version was latency-bound at 32% VALU).
template<bool MASKED>
__global__ __launch_bounds__(256)
void gather2_k(const bf16r* __restrict__ hA, const bf16r* __restrict__ hP,
               bf16r* __restrict__ aggP, bf16r* __restrict__ aggA,
               const int* __restrict__ offAP, const int* __restrict__ bktAP,
               const int* __restrict__ offPA, const int* __restrict__ bktPA,
               const float* __restrict__ mA0, const float* __restrict__ mP0)
{
    int gw = (blockIdx.x * 256 + threadIdx.x) >> 6;
    int lane = threadIdx.x & 63;
    const bf16r* src; bf16r* agg; const int* off; const int* bkt;
    const float* msk; int w;
    if (gw < NPP) { src = hA; agg = aggP; off = offAP; bkt = bktAP; msk = mA0; w = gw; }
    else          { src = hP; agg = aggA; off = offPA; bkt = bktPA; msk = mP0; w = gw - NPP; }
    int s0 = off[w], s1 = off[w + 1];
    float a0 = 0.f, a1 = 0.f, b0 = 0.f, b1 = 0.f;
    int e = s0;
    for (; e + 3 < s1; e += 4) {
        int i0 = bkt[e], i1 = bkt[e + 1], i2 = bkt[e + 2], i3 = bkt[e + 3];
        ushort2 u0 = *(const ushort2*)(src + (size_t)i0 * HD + lane * 2);
        ushort2 u1 = *(const ushort2*)(src + (size_t)i1 * HD + lane * 2);
        ushort2 u2 = *(const ushort2*)(src + (size_t)i2 * HD + lane * 2);
        ushort2 u3 = *(const ushort2*)(src + (size_t)i3 * HD + lane * 2);
        float m0 = 1.f, m1 = 1.f, m2 = 1.f, m3 = 1.f;
        if constexpr (MASKED) {
            m0 = msk[i0] * INV_KEEP; m1 = msk[i1] * INV_KEEP;
            m2 = msk[i2] * INV_KEEP; m3 = msk[i3] * INV_KEEP;
        }
        a0 += m0 * bf2f(u0.x) + m1 * bf2f(u1.x);
        a1 += m0 * bf2f(u0.y) + m1 * bf2f(u1.y);
        b0 += m2 * bf2f(u2.x) + m3 * bf2f(u3.x);
        b1 += m2 * bf2f(u2.y) + m3 * bf2f(u3.y);
    }
    for (; e < s1; ++e) {
        int i0 = bkt[e];
        ushort2 u = *(const ushort2*)(src + (size_t)i0 * HD + lane * 2);
        float m0 = MASKED ? msk[i0] * INV_KEEP : 1.0f;
        a0 += m0 * bf2f(u.x);
        a1 += m0 * bf2f(u.y);
    }
    a0 += b0;
    a1 += b1;
    ushort2 o;
    o.x = f2bf(a0);
    o.y = f2bf(a1);
    *(ushort2*)(agg + (size_t)w * HD + lane * 2) = o;
}

// fallback scatter (atomics, f32 agg)
__global__ __launch_bounds__(256)
void scatter_k(const bf16r* __restrict__ src, float* dst,
               const int* __restrict__ ei, int E)
{
    int g = blockIdx.x * 256 + threadIdx.x;
    int e = g >> 5, lane = g & 31;
    if (e >= E) return;
    int s = ei[e], d = ei[E + e];
    ushort4 u = *(const ushort4*)(src + (size_t)s * HD + lane * 4);
    float* dp = dst + (size_t)d * HD + lane * 4;
    unsafeAtomicAdd(dp + 0, bf2f(u.x));
    unsafeAtomicAdd(dp + 1, bf2f(u.y));
    unsafeAtomicAdd(dp + 2, bf2f(u.z));
    unsafeAtomicAdd(dp + 3, bf2f(u.w));
}

// ================= persistent pipelined MFMA GEMM (512 threads) =================
struct SideP {
    const void* in;       // self input (proj for GIN1M [node-idx], h otherwise)
    bf16r* out;
    const void* agg;      // AT-typed (bf16 main, f32 fallback)
    const bf16r* wt;
    const float* bias;
    const float* epsp;
    float* gsum;
    float* gsumsq;
    const float* gamma;   // GIN2
    const float* beta;    // GIN2
    float invN;           // GIN2
    const float* mask;    // PROJ: [R][Nn]; GIN1M: flat [R*Nn]
    int M, Nn, tiles;
};

// 512-thread blocks, 8 waves x 16-col band. DOUBLE-buffered LDS A-tile with
// ONE barrier per tile: stage(cur) / barrier / prefetch(t+1) / compute(cur)
// / flip. (At VGPR=52 the 32-waves/CU HW cap = 4 blocks/CU is binding; the
// double buffer's 35.8KB LDS still fits 4 blocks -> the 2nd barrier's
// removal is free.) Prefetch stays AFTER the barrier so the compiler's
// vmcnt(0)-at-barrier drain never waits on it.
template<int MODE, typename IT, typename AT>
__global__ __launch_bounds__(512)
void mfma_gemm(SideP P, SideP A, int BP)
{
    __shared__ bf16r za[2][64][LDA];
    __shared__ float red[2][HD];
    const int tid = threadIdx.x;

    SideP S;
    int t, tstride;
    if ((int)blockIdx.x < BP) { S = P; t = blockIdx.x; tstride = BP; }
    else { S = A; t = (int)blockIdx.x - BP; tstride = NB_GEMM - BP; }
    if (t >= S.tiles) return;

    constexpr bool GIN1ANY = (MODE == M_GIN1 || MODE == M_GIN1M);
    constexpr bool PMSK    = (MODE == M_GIN1M);
    constexpr int  NVH     = (MODE == M_PROJ || MODE == M_PROJ1) ? 2 : 1;
    constexpr int  NVA     = (GIN1ANY && sizeof(AT) == 4) ? 2 : 1;

    const int wid = tid >> 6, lane = tid & 63;
    const int lr = lane & 15, lk = (lane >> 4) * 8;
    const int colq = (lane >> 4) * 4;
    const int cb = wid * 16;            // wave's 16-col band
    const int srow = tid >> 4;          // 0..31; chunk i adds 32
    const int scol = (tid & 15) * 8;

    float epsv = 1.0f;
    if (GIN1ANY) epsv = 1.0f + S.epsp[0];

    v8s w[4];
    #pragma unroll
    for (int ks = 0; ks < 4; ++ks)
        w[ks] = *(const v8s*)(S.wt + (size_t)(cb + lr) * HD + ks * 32 + lk);

    const float4 bb = *(const float4*)(S.bias + cb + colq);

    // GIN2: per-thread BN scale/shift for this thread's 8 staging cols
    float sc8[MODE == M_GIN2 ? 8 : 1], sh8[MODE == M_GIN2 ? 8 : 1];
    if constexpr (MODE == M_GIN2) {
        #pragma unroll
        for (int j = 0; j < 8; ++j) {
            int c = scol + j;
            float mu = S.gsum[c] * S.invN;
            float var = S.gsumsq[c] * S.invN - mu * mu;
            float s = S.gamma[c] * rsqrtf(var + BN_EPS);
            sc8[j] = s;
            sh8[j] = S.beta[c] - mu * s;
        }
    }

    float st_s[4], st_q[4];
    if (GIN1ANY) {
        #pragma unroll
        for (int j = 0; j < 4; ++j) { st_s[j] = 0.f; st_q[j] = 0.f; }
    }

    int4 pre[2][NVH];
    int4 preA[2][NVA];
    float mpre[PMSK ? 2 : 1];

    auto prefetch = [&](int tt) {
        int m0n = tt * 64;
        #pragma unroll
        for (int i = 0; i < 2; ++i) {
            int gr = m0n + srow + 32 * i;
            if constexpr (PMSK) {
                // per-row run (Nn not 64-divisible)
                int run = (gr >= S.Nn) + (gr >= 2 * S.Nn) + (gr >= 3 * S.Nn);
                int node = gr - run * S.Nn;
                mpre[i] = S.mask[gr];
                pre[i][0] = *(const int4*)((const bf16r*)S.in + (size_t)node * HD + scol);
            } else if (gr < S.M) {
                const int4* p = (const int4*)((const IT*)S.in + (size_t)gr * HD + scol);
                pre[i][0] = p[0];
                if constexpr (NVH == 2) pre[i][1] = p[1];
            } else {
                pre[i][0] = make_int4(0, 0, 0, 0);
                if constexpr (NVH == 2) pre[i][1] = make_int4(0, 0, 0, 0);
            }
            if constexpr (GIN1ANY) {
                if (gr < S.Nn) {
                    const int4* pa = (const int4*)((const AT*)S.agg + (size_t)gr * HD + scol);
                    preA[i][0] = pa[0];
                    if constexpr (NVA == 2) preA[i][1] = pa[1];
                } else {
                    preA[i][0] = make_int4(0, 0, 0, 0);
                    if constexpr (NVA == 2) preA[i][1] = make_int4(0, 0, 0, 0);
                }
            }
        }
    };

    prefetch(t);

    int cur = 0;
    for (;;) {
        const int m0 = t * 64;
        // ---- stage into za[cur] ----
        #pragma unroll
        for (int i = 0; i < 2; ++i) {
            int row = srow + 32 * i;
            float v[8];
            if constexpr (NVH == 2) {
                const float* pf = (const float*)&pre[i][0];
                #pragma unroll
                for (int j = 0; j < 8; ++j) v[j] = pf[j];
            } else {
                const bf16r* pu = (const bf16r*)&pre[i][0];
                #pragma unroll
                for (int j = 0; j < 8; ++j) v[j] = bf2f(pu[j]);
            }
            if constexpr (GIN1ANY) {
                float av[8];
                if constexpr (sizeof(AT) == 4) {
                    const float* pa = (const float*)&preA[i][0];
                    #pragma unroll
                    for (int j = 0; j < 8; ++j) av[j] = pa[j];
                } else {
                    const bf16r* pa = (const bf16r*)&preA[i][0];
                    #pragma unroll
                    for (int j = 0; j < 8; ++j) av[j] = bf2f(pa[j]);
                }
                float coef = epsv;
                if constexpr (PMSK) coef = mpre[i] * INV_KEEP * epsv;
                #pragma unroll
                for (int j = 0; j < 8; ++j) v[j] = v[j] * coef + av[j];
            } else if constexpr (MODE == M_GIN2) {
                #pragma unroll
                for (int j = 0; j < 8; ++j)
                    v[j] = fmaxf(v[j] * sc8[j] + sh8[j], 0.f);
            }
            union { v8s w8; bf16r u[8]; } pk;
            #pragma unroll
            for (int j = 0; j < 8; ++j) pk.u[j] = f2bf(v[j]);
            *(v8s*)&za[cur][row][scol] = pk.w8;
        }
        __syncthreads();

        // ---- prefetch next tile (after barrier -> stays in flight) ----
        const int tn = t + tstride;
        const bool more = tn < S.tiles;
        if (more) prefetch(tn);

        // ---- compute: wave's 16-col band x 64 rows ----
        v4f acc[4];
        #pragma unroll
        for (int rf = 0; rf < 4; ++rf) acc[rf] = (v4f){0.f, 0.f, 0.f, 0.f};

        #pragma unroll
        for (int ks = 0; ks < 4; ++ks)
            #pragma unroll
            for (int rf = 0; rf < 4; ++rf) {
                v8s a = *(const v8s*)&za[cur][rf * 16 + lr][ks * 32 + lk];
                acc[rf] = __builtin_amdgcn_mfma_f32_16x16x32_bf16(w[ks], a, acc[rf], 0, 0, 0);
            }

        #pragma unroll
        for (int rf = 0; rf < 4; ++rf) {
            acc[rf][0] += bb.x; acc[rf][1] += bb.y;
            acc[rf][2] += bb.z; acc[rf][3] += bb.w;
        }

        if constexpr (MODE == M_PROJ) {
            #pragma unroll
            for (int rf = 0; rf < 4; ++rf) {
                int grow = m0 + rf * 16 + lr;
                if (grow < S.M) {
                    #pragma unroll
                    for (int run = 0; run < NRUNS; ++run) {
                        float wm = S.mask[(size_t)run * S.Nn + grow] * INV_KEEP;
                        ushort4 o;
                        o.x = f2bf(acc[rf][0] * wm);
                        o.y = f2bf(acc[rf][1] * wm);
                        o.z = f2bf(acc[rf][2] * wm);
                        o.w = f2bf(acc[rf][3] * wm);
                        *(ushort4*)(S.out + ((size_t)run * S.Nn + grow) * HD + cb + colq) = o;
                    }
                }
            }
        } else if constexpr (MODE == M_PROJ1) {
            #pragma unroll
            for (int rf = 0; rf < 4; ++rf) {
                int grow = m0 + rf * 16 + lr;
                if (grow < S.M) {
                    ushort4 o;
                    o.x = f2bf(acc[rf][0]);
                    o.y = f2bf(acc[rf][1]);
                    o.z = f2bf(acc[rf][2]);
                    o.w = f2bf(acc[rf][3]);
                    *(ushort4*)(S.out + (size_t)grow * HD + cb + colq) = o;
                }
            }
        } else if constexpr (GIN1ANY) {
            #pragma unroll
            for (int rf = 0; rf < 4; ++rf) {
                int grow = m0 + rf * 16 + lr;
                ushort4 o;
                o.x = f2bf(acc[rf][0]);
                o.y = f2bf(acc[rf][1]);
                o.z = f2bf(acc[rf][2]);
                o.w = f2bf(acc[rf][3]);
                *(ushort4*)(S.out + (size_t)grow * HD + cb + colq) = o;
            }
            #pragma unroll
            for (int j = 0; j < 4; ++j)
                #pragma unroll
                for (int rf = 0; rf < 4; ++rf) {
                    float vv = acc[rf][j];
                    st_s[j] += vv;
                    st_q[j] += vv * vv;
                }
        } else {  // M_GIN2
            #pragma unroll
            for (int rf = 0; rf < 4; ++rf) {
                int grow = m0 + rf * 16 + lr;
                ushort4 o;
                o.x = f2bf(fmaxf(acc[rf][0], 0.f));
                o.y = f2bf(fmaxf(acc[rf][1], 0.f));
                o.z = f2bf(fmaxf(acc[rf][2], 0.f));
                o.w = f2bf(fmaxf(acc[rf][3], 0.f));
                *(ushort4*)(S.out + (size_t)grow * HD + cb + colq) = o;
            }
        }

        if (!more) break;
        t = tn;
        cur ^= 1;
        // double buffer: next stage writes the other half; waves that might
        // lap (write za[cur] again) must first pass the NEXT barrier, by
        // which time this buffer's readers have drained (lgkmcnt at barrier).
    }

    if constexpr (GIN1ANY) {
        // reduce stats over the 16 lr lanes of each 16-lane group
        #pragma unroll
        for (int d = 1; d < 16; d <<= 1)
            #pragma unroll
            for (int j = 0; j < 4; ++j) {
                st_s[j] += __shfl_xor(st_s[j], d);
                st_q[j] += __shfl_xor(st_q[j], d);
            }
        if (lr == 0) {
            #pragma unroll
            for (int j = 0; j < 4; ++j) {
                red[0][cb + colq + j] = st_s[j];
                red[1][cb + colq + j] = st_q[j];
            }
        }
        __syncthreads();
        if (tid < HD) {
            unsafeAtomicAdd(S.gsum + tid, red[0][tid]);
            unsafeAtomicAdd(S.gsumsq + tid, red[1][tid]);
        }
    }
}

// mean over runs + [128]x[128,4] matmul
__global__ __launch_bounds__(256)
void final_k(const bf16r* __restrict__ ha, const float* __restrict__ fw,
             const float* __restrict__ fb, float* __restrict__ out)
{
    int g = blockIdx.x * 256 + threadIdx.x;
    int node = g >> 6, lane = g & 63;
    if (node >= NAU) return;
    float m0 = 0.f, m1 = 0.f;
    #pragma unroll
    for (int r = 0; r < NRUNS; ++r) {
        size_t base = ((size_t)r * NAU + node) * HD;
        m0 += bf2f(ha[base + lane]);
        m1 += bf2f(ha[base + 64 + lane]);
    }
    m0 *= 0.25f;
    m1 *= 0.25f;
    float p[4];
    #pragma unroll
    for (int c = 0; c < 4; ++c)
        p[c] = m0 * fw[lane * 4 + c] + m1 * fw[(lane + 64) * 4 + c];
    #pragma unroll
    for (int off = 32; off >= 1; off >>= 1)
        #pragma unroll
        for (int c = 0; c < 4; ++c) p[c] += __shfl_down(p[c], off);
    if (lane == 0) {
        #pragma unroll
        for (int c = 0; c < 4; ++c) out[(size_t)node * 4 + c] = p[c] + fb[c];
    }
}

#define CSR_INTS ((size_t)(NPP + 4) + NEDGE + (NAU + 4) + NEDGE)
#define WT_ELEMS ((size_t)10 * HD * HD)

template<bool GATHER>
static void run_all(void* const* d_in, void* d_out, void* d_ws, hipStream_t stream)
{
    const float* x_author = (const float*)d_in[0];
    const float* x_paper  = (const float*)d_in[1];
    const int*   ei_ap    = (const int*)d_in[2];
    const int*   ei_pa    = (const int*)d_in[3];
    const float* drop_a   = (const float*)d_in[4];
    const float* drop_p   = (const float*)d_in[5];
    const float* lin_a_w  = (const float*)d_in[6];
    const float* lin_a_b  = (const float*)d_in[7];
    const float* lin_p_w  = (const float*)d_in[8];
    const float* lin_p_b  = (const float*)d_in[9];
    const float* W1       = (const float*)d_in[10];
    const float* B1       = (const float*)d_in[11];
    const float* G        = (const float*)d_in[12];
    const float* BT       = (const float*)d_in[13];
    const float* W2       = (const float*)d_in[14];
    const float* B2       = (const float*)d_in[15];
    const float* EPS      = (const float*)d_in[16];
    const float* fw       = (const float*)d_in[17];
    const float* fb       = (const float*)d_in[18];

    // ws: [stats 8*HD f32 (4 sets)][Wt][CSR?][agg][proj?][h_a][h_p]
    float* stats = (float*)d_ws;                  // set t: gsum=stats+t*2*HD
    bf16r* wt = (bf16r*)(stats + 8 * HD);
    char* cp = (char*)(wt + WT_ELEMS);

    int *off_ap = nullptr, *bkt_ap = nullptr, *off_pa = nullptr, *bkt_pa = nullptr;
    if (GATHER) {
        int* ip = (int*)cp;
        off_ap = ip;  ip += NPP + 4;
        bkt_ap = ip;  ip += NEDGE;
        off_pa = ip;  ip += NAU + 4;
        bkt_pa = ip;  ip += NEDGE;
        cp = (char*)ip;
    }
    void* agg_a_v = cp;
    size_t aggElem = GATHER ? sizeof(bf16r) : sizeof(float);
    void* agg_p_v = cp + (size_t)NAU * HD * aggElem;
    cp += (size_t)(NAU + NPP) * HD * aggElem;
    bf16r* proj_a = nullptr; bf16r* proj_p = nullptr;
    if (GATHER) {
        proj_a = (bf16r*)cp;  cp += (size_t)NAU * HD * sizeof(bf16r);
        proj_p = (bf16r*)cp;  cp += (size_t)NPP * HD * sizeof(bf16r);
    }
    bf16r* h_a = (bf16r*)cp;
    bf16r* h_p = h_a + (size_t)NRUNS * NAU * HD;

    const bf16r* wt_lin_a = wt;
    const bf16r* wt_lin_p = wt + (size_t)1 * HD * HD;
    const bf16r* wt_W1    = wt + (size_t)2 * HD * HD;
    const bf16r* wt_W2    = wt + (size_t)6 * HD * HD;

    // CSR cur arrays alias agg region (dead until first gather)
    int* cur_ap = (int*)agg_a_v;
    int* cur_pa = cur_ap + NPP;
    int* partial = cur_pa + NAU;

    convw_prep_k<<<788, 256, 0, stream>>>(lin_a_w, lin_p_w, W1, W2, wt, stats,
                                          (float*)cur_ap, (NPP + NAU) / 4);

    if (GATHER) {
        count2_k<<<(2 * NEDGE + 255) / 256, 256, 0, stream>>>(ei_ap, ei_pa, cur_ap, cur_pa);
        scan1m_k<<<C_AP + C_PA, 256, 0, stream>>>(cur_ap, off_ap, cur_pa, off_pa, partial);
        scan2m_k<<<2, 256, 0, stream>>>(partial);
        scan3m_k<<<C_AP + C_PA, 256, 0, stream>>>(off_ap, cur_ap, off_pa, cur_pa, partial);
        fill2_k<<<(2 * NEDGE + 255) / 256, 256, 0, stream>>>(ei_ap, ei_pa,
                                                             cur_ap, bkt_ap, cur_pa, bkt_pa);
    }

    const int TP = NRUNS * NPP / 64, TA = NRUNS * NAU / 64;
    const int BPgin = (int)((long)NB_GEMM * TP / (TP + TA));

    if (GATHER) {
        // ---- single-copy PROJ ----
        SideP Pp = {}, Pa = {};
        Pp.in = x_paper; Pp.out = proj_p; Pp.wt = wt_lin_p; Pp.bias = lin_p_b;
        Pp.M = NPP; Pp.Nn = NPP; Pp.tiles = (NPP + 63) / 64;
        Pa.in = x_author; Pa.out = proj_a; Pa.wt = wt_lin_a; Pa.bias = lin_a_b;
        Pa.M = NAU; Pa.Nn = NAU; Pa.tiles = (NAU + 63) / 64;
        int BPproj = (int)((long)NB_GEMM * Pp.tiles / (Pp.tiles + Pa.tiles));
        mfma_gemm<M_PROJ1, float, float><<<NB_GEMM, 512, 0, stream>>>(Pp, Pa, BPproj);

        for (int l = 0; l < 2; ++l) {
            int t0 = l * 2 + 0, t1 = l * 2 + 1;

            if (l == 0) {
                gather2_k<true><<<((NPP + NAU) * 64) / 256, 256, 0, stream>>>(
                    proj_a, proj_p, (bf16r*)agg_p_v, (bf16r*)agg_a_v,
                    off_ap, bkt_ap, off_pa, bkt_pa, drop_a, drop_p);
            } else {
                gather2_k<false><<<((NPP + NAU) * 64) / 256, 256, 0, stream>>>(
                    h_a, h_p, (bf16r*)agg_p_v, (bf16r*)agg_a_v,
                    off_ap, bkt_ap, off_pa, bkt_pa, nullptr, nullptr);
            }

            SideP G1p = {}, G1a = {};
            G1p.wt = wt_W1 + (size_t)t0 * HD * HD;
            G1p.bias = B1 + (size_t)t0 * HD; G1p.epsp = EPS + t0;
            G1p.agg = agg_p_v;
            G1p.gsum = stats + t0 * 2 * HD; G1p.gsumsq = G1p.gsum + HD;
            G1p.M = NRUNS * NPP; G1p.Nn = NPP; G1p.tiles = TP; G1p.out = h_p;
            G1a.wt = wt_W1 + (size_t)t1 * HD * HD;
            G1a.bias = B1 + (size_t)t1 * HD; G1a.epsp = EPS + t1;
            G1a.agg = agg_a_v;
            G1a.gsum = stats + t1 * 2 * HD; G1a.gsumsq = G1a.gsum + HD;
            G1a.M = NRUNS * NAU; G1a.Nn = NAU; G1a.tiles = TA; G1a.out = h_a;
            if (l == 0) {
                G1p.in = proj_p; G1p.mask = drop_p;
                G1a.in = proj_a; G1a.mask = drop_a;
                mfma_gemm<M_GIN1M, bf16r, bf16r><<<NB_GEMM, 512, 0, stream>>>(G1p, G1a, BPgin);
            } else {
                G1p.in = h_p;
                G1a.in = h_a;
                mfma_gemm<M_GIN1, bf16r, bf16r><<<NB_GEMM, 512, 0, stream>>>(G1p, G1a, BPgin);
            }

            SideP G2p = {}, G2a = {};
            G2p.in = h_p; G2p.out = h_p; G2p.wt = wt_W2 + (size_t)t0 * HD * HD;
            G2p.bias = B2 + (size_t)t0 * HD;
            G2p.gsum = stats + t0 * 2 * HD; G2p.gsumsq = G2p.gsum + HD;
            G2p.gamma = G + (size_t)t0 * HD; G2p.beta = BT + (size_t)t0 * HD;
            G2p.invN = 1.0f / (NRUNS * NPP);
            G2p.M = NRUNS * NPP; G2p.Nn = NPP; G2p.tiles = TP;
            G2a.in = h_a; G2a.out = h_a; G2a.wt = wt_W2 + (size_t)t1 * HD * HD;
            G2a.bias = B2 + (size_t)t1 * HD;
            G2a.gsum = stats + t1 * 2 * HD; G2a.gsumsq = G2a.gsum + HD;
            G2a.gamma = G + (size_t)t1 * HD; G2a.beta = BT + (size_t)t1 * HD;
            G2a.invN = 1.0f / (NRUNS * NAU);
            G2a.M = NRUNS * NAU; G2a.Nn = NAU; G2a.tiles = TA;
            mfma_gemm<M_GIN2, bf16r, float><<<NB_GEMM, 512, 0, stream>>>(G2p, G2a, BPgin);
        }
    } else {
        // fallback: masked 4-copy PROJ + atomic scatter + f32 agg GIN1
        SideP Pp = {}, Pa = {};
        Pp.in = x_paper; Pp.out = h_p; Pp.wt = wt_lin_p; Pp.bias = lin_p_b;
        Pp.mask = drop_p; Pp.M = NPP; Pp.Nn = NPP; Pp.tiles = (NPP + 63) / 64;
        Pa.in = x_author; Pa.out = h_a; Pa.wt = wt_lin_a; Pa.bias = lin_a_b;
        Pa.mask = drop_a; Pa.M = NAU; Pa.Nn = NAU; Pa.tiles = (NAU + 63) / 64;
        int BPproj = (int)((long)NB_GEMM * Pp.tiles / (Pp.tiles + Pa.tiles));
        mfma_gemm<M_PROJ, float, float><<<NB_GEMM, 512, 0, stream>>>(Pp, Pa, BPproj);

        for (int l = 0; l < 2; ++l) {
            int t0 = l * 2 + 0, t1 = l * 2 + 1;
            zero_k<<<2048, 256, 0, stream>>>((float*)agg_a_v, ((size_t)(NAU + NPP) * HD) / 4);
            scatter_k<<<(NEDGE * 32) / 256, 256, 0, stream>>>(h_a, (float*)agg_p_v, ei_ap, NEDGE);
            scatter_k<<<(NEDGE * 32) / 256, 256, 0, stream>>>(h_p, (float*)agg_a_v, ei_pa, NEDGE);

            SideP G1p = {}, G1a = {};
            G1p.in = h_p; G1p.out = h_p; G1p.wt = wt_W1 + (size_t)t0 * HD * HD;
            G1p.bias = B1 + (size_t)t0 * HD; G1p.agg = agg_p_v; G1p.epsp = EPS + t0;
            G1p.gsum = stats + t0 * 2 * HD; G1p.gsumsq = G1p.gsum + HD;
            G1p.M = NRUNS * NPP; G1p.Nn = NPP; G1p.tiles = TP;
            G1a.in = h_a; G1a.out = h_a; G1a.wt = wt_W1 + (size_t)t1 * HD * HD;
            G1a.bias = B1 + (size_t)t1 * HD; G1a.agg = agg_a_v; G1a.epsp = EPS + t1;
            G1a.gsum = stats + t1 * 2 * HD; G1a.gsumsq = G1a.gsum + HD;
            G1a.M = NRUNS * NAU; G1a.Nn = NAU; G1a.tiles = TA;
            mfma_gemm<M_GIN1, bf16r, float><<<NB_GEMM, 512, 0, stream>>>(G1p, G1a, BPgin);

            SideP G2p = {}, G2a = {};
            G2p.in = h_p; G2p.out = h_p;
            G2p.wt = wt_W2 + (size_t)t0 * HD * HD; G2p.bias = B2 + (size_t)t0 * HD;
            G2p.gsum = stats + t0 * 2 * HD; G2p.gsumsq = G2p.gsum + HD;
            G2p.gamma = G + (size_t)t0 * HD; G2p.beta = BT + (size_t)t0 * HD;
            G2p.invN = 1.0f / (NRUNS * NPP);
            G2p.M = NRUNS * NPP; G2p.Nn = NPP; G2p.tiles = TP;
            G2a.in = h_a; G2a.out = h_a;
            G2a.wt = wt_W2 + (size_t)t1 * HD * HD; G2a.bias = B2 + (size_t)t1 * HD;
            G2a.gsum = stats + t1 * 2 * HD; G2a.gsumsq = G2a.gsum + HD;
            G2a.gamma = G + (size_t)t1 * HD; G2a.beta = BT + (size_t)t1 * HD;
            G2a.invN = 1.0f / (NRUNS * NAU);
            G2a.M = NRUNS * NAU; G2a.Nn = NAU; G2a.tiles = TA;
            mfma_gemm<M_GIN2, bf16r, float><<<NB_GEMM, 512, 0, stream>>>(G2p, G2a, BPgin);
        }
    }

    final_k<<<(NAU * 64) / 256, 256, 0, stream>>>(h_a, fw, fb, (float*)d_out);
}

extern "C" void kernel_launch(void* const* d_in, const int* in_sizes, int n_in,
                              void* d_out, int out_size, void* d_ws, size_t ws_size,
                              hipStream_t stream)
{
    const size_t hB    = (size_t)NRUNS * (NAU + NPP) * HD * sizeof(bf16r);
    const size_t statB = 8 * HD * sizeof(float);
    const size_t wtB   = WT_ELEMS * sizeof(bf16r);
    const size_t csrB  = CSR_INTS * sizeof(int);
    const size_t aggBF = (size_t)(NAU + NPP) * HD * sizeof(bf16r);
    const size_t projB = (size_t)(NAU + NPP) * HD * sizeof(bf16r);

    const size_t need_gather = statB + wtB + csrB + aggBF + projB + hB;  // ~235.3 MB
    if (ws_size >= need_gather) {
        run_all<true>(d_in, d_out, d_ws, stream);
    } else {
        run_all<false>(d_in, d_out, d_ws, stream);   // atomic fallback
    }
}